// Round 1
// baseline (667.041 us; speedup 1.0000x reference)
//
#include <hip/hip_runtime.h>
#include <math.h>

#define BB 8
#define AA 19248
#define GG 32
#define CC 81
#define PP 32
#define PHW 19044   /* 138*138 */
#define KPOS 128
#define NEGRATIO 3
#define SELCAP 7680

// ---------------------------------------------------------------------------
// IoU helper — contraction off so K1 and K2 produce bitwise-identical values
// and FMA fusion can't flip threshold/argmax decisions vs the XLA reference.
// ---------------------------------------------------------------------------
__device__ __forceinline__ float iou_one(float ax1, float ay1, float ax2, float ay2,
                                         float areaA,
                                         float gx1, float gy1, float gx2, float gy2) {
#pragma clang fp contract(off)
    float ix1 = fmaxf(ax1, gx1), iy1 = fmaxf(ay1, gy1);
    float ix2 = fminf(ax2, gx2), iy2 = fminf(ay2, gy2);
    float iw = fmaxf(ix2 - ix1, 0.0f), ih = fmaxf(iy2 - iy1, 0.0f);
    float inter = iw * ih;
    float areaB = (gx2 - gx1) * (gy2 - gy1);
    float u = areaA + areaB - inter;
    u = fmaxf(u, 1e-6f);
    return inter / u;
}

// ---------------------------------------------------------------------------
// K1: per (b,a) best IoU + first-max argmax over the 32 GT boxes.
// ---------------------------------------------------------------------------
__global__ void k1_best_per_anchor(const float* __restrict__ anchors,
                                   const float* __restrict__ gt_boxes,
                                   float* __restrict__ best_iou,
                                   int* __restrict__ best_g) {
#pragma clang fp contract(off)
    int b = blockIdx.y;
    int a = blockIdx.x * 256 + threadIdx.x;
    __shared__ float sg[GG][4];
    for (int t = threadIdx.x; t < GG * 4; t += 256)
        sg[t >> 2][t & 3] = gt_boxes[b * GG * 4 + t] / 550.0f;
    __syncthreads();
    if (a >= AA) return;
    float4 an = ((const float4*)anchors)[a];
    float ax1 = an.x - an.z * 0.5f, ay1 = an.y - an.w * 0.5f;
    float ax2 = an.x + an.z * 0.5f, ay2 = an.y + an.w * 0.5f;
    float areaA = (ax2 - ax1) * (ay2 - ay1);
    float best = -1.0f; int bi = 0;
    for (int g = 0; g < GG; ++g) {
        float v = iou_one(ax1, ay1, ax2, ay2, areaA, sg[g][0], sg[g][1], sg[g][2], sg[g][3]);
        if (v > best) { best = v; bi = g; }  // strict > keeps FIRST max (jnp.argmax)
    }
    best_iou[b * AA + a] = best;
    best_g[b * AA + a] = bi;
}

// ---------------------------------------------------------------------------
// K2: per (b,g) argmax over all anchors (first occurrence on ties -> packed
// key with inverted index, take max).
// ---------------------------------------------------------------------------
__global__ void k2_best_anchor_per_gt(const float* __restrict__ anchors,
                                      const float* __restrict__ gt_boxes,
                                      int* __restrict__ best_anchor) {
#pragma clang fp contract(off)
    int b = blockIdx.y, g = blockIdx.x;
    float gx1 = gt_boxes[(b * GG + g) * 4 + 0] / 550.0f;
    float gy1 = gt_boxes[(b * GG + g) * 4 + 1] / 550.0f;
    float gx2 = gt_boxes[(b * GG + g) * 4 + 2] / 550.0f;
    float gy2 = gt_boxes[(b * GG + g) * 4 + 3] / 550.0f;
    unsigned long long lk = 0ULL;
    const float4* a4 = (const float4*)anchors;
    for (int a = threadIdx.x; a < AA; a += 256) {
        float4 an = a4[a];
        float ax1 = an.x - an.z * 0.5f, ay1 = an.y - an.w * 0.5f;
        float ax2 = an.x + an.z * 0.5f, ay2 = an.y + an.w * 0.5f;
        float areaA = (ax2 - ax1) * (ay2 - ay1);
        float v = iou_one(ax1, ay1, ax2, ay2, areaA, gx1, gy1, gx2, gy2);
        unsigned long long key =
            ((unsigned long long)__float_as_uint(v) << 32) | (unsigned)(AA - 1 - a);
        if (key > lk) lk = key;
    }
    for (int off = 32; off; off >>= 1) {
        unsigned long long o = __shfl_xor(lk, off);
        if (o > lk) lk = o;
    }
    __shared__ unsigned long long sk[4];
    if ((threadIdx.x & 63) == 0) sk[threadIdx.x >> 6] = lk;
    __syncthreads();
    if (threadIdx.x == 0) {
        unsigned long long m = sk[0];
        for (int i = 1; i < 4; ++i) if (sk[i] > m) m = sk[i];
        best_anchor[b * GG + g] = AA - 1 - (int)(unsigned)(m & 0xffffffffu);
    }
}

// ---------------------------------------------------------------------------
// K3: per image — apply scatter overrides (pos=true, gidx=g, last/largest g
// wins on duplicates = XLA-CPU scatter order), count positives, compact
// positive keys for top-k, inclusive-scan the hard-negative mask and cap it.
// selmask: 0 = unused, 1 = neg, 2 = pos.
// ---------------------------------------------------------------------------
__global__ __launch_bounds__(1024) void k3_match_scan(
    const float* __restrict__ best_iou, const int* __restrict__ best_g_in,
    const int* __restrict__ best_anchor,
    int* __restrict__ gidx_out, int* __restrict__ selmask,
    unsigned long long* __restrict__ pos_key,
    int* __restrict__ pos_cnt, int* __restrict__ g_npos) {
#pragma clang fp contract(off)
    int b = blockIdx.x;
    int tid = threadIdx.x;
    __shared__ int sba[GG];
    __shared__ int s_cnt;
    __shared__ int s_ws[16];
    __shared__ int s_tot;
    if (tid < GG) sba[tid] = best_anchor[b * GG + tid];
    if (tid == 0) s_cnt = 0;
    __syncthreads();

    for (int a = tid; a < AA; a += 1024) {
        float biou = best_iou[b * AA + a];
        int gi = best_g_in[b * AA + a];
        bool p = (biou >= 0.5f);
        for (int g = 0; g < GG; ++g)
            if (sba[g] == a) { p = true; gi = g; }   // ascending -> last wins
        bool npre = (biou < 0.4f) && !p;
        gidx_out[b * AA + a] = gi;
        selmask[b * AA + a] = p ? 2 : (npre ? 1 : 0);
        if (p) {
            int slot = atomicAdd(&s_cnt, 1);
            unsigned long long key =
                ((unsigned long long)__float_as_uint(biou + 1.0f) << 32) |
                (unsigned)(AA - 1 - a);
            pos_key[(size_t)b * AA + slot] = key;
        }
    }
    __syncthreads();
    int npos = s_cnt;
    if (tid == 0) { pos_cnt[b] = npos; atomicAdd(g_npos, npos); }
    int cap = npos * NEGRATIO;

    // inclusive scan over neg-pre mask, drop entries beyond cap
    int lane = tid & 63, wid = tid >> 6;
    int running = 0;
    for (int base = 0; base < AA; base += 1024) {
        int a = base + tid;
        int v = 0;
        if (a < AA && selmask[b * AA + a] == 1) v = 1;
        int c = v;
        #pragma unroll
        for (int d = 1; d < 64; d <<= 1) {
            int t = __shfl_up(c, d);
            if (lane >= d) c += t;
        }
        if (lane == 63) s_ws[wid] = c;
        __syncthreads();
        if (tid == 0) {
            int run = 0;
            for (int i = 0; i < 16; ++i) { int t = s_ws[i]; s_ws[i] = run; run += t; }
            s_tot = run;
        }
        __syncthreads();
        int cum = running + s_ws[wid] + c;   // inclusive cumsum
        if (v && cum > cap) selmask[b * AA + a] = 0;
        running += s_tot;
        __syncthreads();
    }
}

// ---------------------------------------------------------------------------
// K4: focal classification loss. One 64-lane group per (pos|neg) row.
// ---------------------------------------------------------------------------
__global__ void k4_focal(const float* __restrict__ cls_p, const int* __restrict__ gtl,
                         const int* __restrict__ gidx, const int* __restrict__ selmask,
                         float* __restrict__ acc_cls) {
    int r = blockIdx.x * 4 + (threadIdx.x >> 6);
    int lane = threadIdx.x & 63;
    int sm = selmask[r];
    if (sm == 0) return;
    int b = r / AA;
    const float* x = cls_p + (size_t)r * CC;
    float e0 = x[lane];
    float e1 = (lane < CC - 64) ? x[64 + lane] : -3.0e38f;
    float m = fmaxf(e0, e1);
    for (int off = 32; off; off >>= 1) m = fmaxf(m, __shfl_xor(m, off));
    float s = expf(e0 - m) + ((lane < CC - 64) ? expf(e1 - m) : 0.0f);
    for (int off = 32; off; off >>= 1) s += __shfl_xor(s, off);
    if (lane == 0) {
        int lbl = (sm == 2) ? gtl[b * GG + gidx[r]] : 0;
        float pt = expf(x[lbl] - m) / s;
        pt = fminf(fmaxf(pt, 1e-6f), 1.0f - 1e-6f);
        float at = (lbl > 0) ? 0.25f : 0.75f;
        float om = 1.0f - pt;
        float f = at * om * om * (-logf(pt));
        atomicAdd(acc_cls, f);
    }
}

// ---------------------------------------------------------------------------
// K5: box regression loss (smooth L1 on encoded targets), positives only.
// ---------------------------------------------------------------------------
__global__ void k5_box(const float* __restrict__ box_p, const float* __restrict__ anchors,
                       const float* __restrict__ gt_boxes, const int* __restrict__ gidx,
                       const int* __restrict__ selmask, float* __restrict__ acc_box) {
#pragma clang fp contract(off)
    int r = blockIdx.x * 256 + threadIdx.x;
    if (r >= BB * AA) return;
    if (selmask[r] != 2) return;
    int b = r / AA, a = r - b * AA;
    int g = gidx[r];
    float m0 = gt_boxes[(b * GG + g) * 4 + 0] / 550.0f;
    float m1 = gt_boxes[(b * GG + g) * 4 + 1] / 550.0f;
    float m2 = gt_boxes[(b * GG + g) * 4 + 2] / 550.0f;
    float m3 = gt_boxes[(b * GG + g) * 4 + 3] / 550.0f;
    float4 an = ((const float4*)anchors)[a];
    float gcx = 0.5f * (m0 + m2), gcy = 0.5f * (m1 + m3);
    float gw = fmaxf(m2 - m0, 1e-6f), gh = fmaxf(m3 - m1, 1e-6f);
    float t0 = (gcx - an.x) / (an.z * 0.1f);
    float t1 = (gcy - an.y) / (an.w * 0.1f);
    float t2 = logf(gw / an.z) / 0.2f;
    float t3 = logf(gh / an.w) / 0.2f;
    const float* bp = box_p + (size_t)r * 4;
    float l = 0.0f, d;
    d = fabsf(bp[0] - t0); l += (d < 1.0f) ? 0.5f * d * d : d - 0.5f;
    d = fabsf(bp[1] - t1); l += (d < 1.0f) ? 0.5f * d * d : d - 0.5f;
    d = fabsf(bp[2] - t2); l += (d < 1.0f) ? 0.5f * d * d : d - 0.5f;
    d = fabsf(bp[3] - t3); l += (d < 1.0f) ? 0.5f * d * d : d - 0.5f;
    atomicAdd(acc_box, l);
}

// ---------------------------------------------------------------------------
// K6: per-image top-min(npos,128) selection by packed key (value desc, index
// asc) via repeated block-argmax over the compacted positive list (LDS-
// resident when it fits). Gathers selected coeffs + matched gt index.
// ---------------------------------------------------------------------------
__global__ __launch_bounds__(1024) void k6_select(
    unsigned long long* __restrict__ pos_key, const int* __restrict__ pos_cnt,
    const int* __restrict__ gidx, const float* __restrict__ coeffs,
    int* __restrict__ sel_g, float* __restrict__ sel_coef, int* __restrict__ sel_cnt) {
    int b = blockIdx.x, tid = threadIdx.x;
    __shared__ unsigned long long s_keys[SELCAP];
    __shared__ unsigned long long s_red[16];
    __shared__ unsigned long long s_max;
    __shared__ int s_sel_a[KPOS];
    int n = pos_cnt[b];
    bool use_lds = (n <= SELCAP);
    unsigned long long* keys;
    if (use_lds) {
        for (int i = tid; i < n; i += 1024) s_keys[i] = pos_key[(size_t)b * AA + i];
        keys = s_keys;
    } else {
        keys = pos_key + (size_t)b * AA;
    }
    __syncthreads();
    int lane = tid & 63, wid = tid >> 6;
    int rounds = (n < KPOS) ? n : KPOS;
    for (int r = 0; r < rounds; ++r) {
        unsigned long long lk = 0ULL;
        for (int i = tid; i < n; i += 1024) { unsigned long long k = keys[i]; if (k > lk) lk = k; }
        for (int off = 32; off; off >>= 1) {
            unsigned long long o = __shfl_xor(lk, off);
            if (o > lk) lk = o;
        }
        if (lane == 0) s_red[wid] = lk;
        __syncthreads();
        if (tid == 0) {
            unsigned long long m = 0ULL;
            for (int i = 0; i < 16; ++i) if (s_red[i] > m) m = s_red[i];
            s_max = m;
        }
        __syncthreads();
        unsigned long long m = s_max;
        if (tid == 0) s_sel_a[r] = AA - 1 - (int)(unsigned)(m & 0xffffffffu);
        for (int i = tid; i < n; i += 1024) if (keys[i] == m) keys[i] = 0ULL;  // unique
        __syncthreads();
    }
    if (tid == 0) sel_cnt[b] = rounds;
    __syncthreads();
    for (int t = tid; t < rounds * PP; t += 1024) {
        int k = t >> 5, p = t & 31;
        int a = s_sel_a[k];
        sel_coef[(b * KPOS + k) * PP + p] = coeffs[((size_t)(b * AA + a)) * PP + p];
    }
    for (int t = tid; t < rounds; t += 1024)
        sel_g[b * KPOS + t] = gidx[b * AA + s_sel_a[t]];
}

// ---------------------------------------------------------------------------
// K7: mask loss — logits = coeffs_sel(<=128 x 32) x protos(32 x 19044) + BCE,
// protos held in registers per pixel, coeffs in LDS, one pass over pixels.
// All selected entries have w=1 so sum raw BCE and divide by PHW at the end.
// ---------------------------------------------------------------------------
__global__ __launch_bounds__(256) void k7_mask(
    const float* __restrict__ protos, const float* __restrict__ gtm,
    const float* __restrict__ sel_coef, const int* __restrict__ sel_g,
    const int* __restrict__ sel_cnt, float* __restrict__ acc_mask) {
    int b = blockIdx.y;
    int pix = blockIdx.x * 256 + threadIdx.x;
    __shared__ float s_c[KPOS * PP];
    __shared__ int s_g[KPOS];
    __shared__ float s_red[4];
    int nk = sel_cnt[b];
    for (int t = threadIdx.x; t < nk * PP; t += 256) s_c[t] = sel_coef[b * KPOS * PP + t];
    for (int t = threadIdx.x; t < nk; t += 256) s_g[t] = sel_g[b * KPOS + t];
    __syncthreads();
    bool valid = pix < PHW;
    float pr[PP];
    #pragma unroll
    for (int p = 0; p < PP; ++p)
        pr[p] = valid ? protos[((size_t)(b * PP + p)) * PHW + pix] : 0.0f;
    float acc = 0.0f;
    for (int k = 0; k < nk; ++k) {
        const float* c = &s_c[k * PP];
        float l = 0.0f;
        #pragma unroll
        for (int p = 0; p < PP; ++p) l += c[p] * pr[p];
        float t = valid ? gtm[((size_t)(b * GG + s_g[k])) * PHW + pix] : 0.0f;
        float bce = fmaxf(l, 0.0f) - l * t + log1pf(expf(-fabsf(l)));
        if (valid) acc += bce;
    }
    for (int off = 32; off; off >>= 1) acc += __shfl_xor(acc, off);
    if ((threadIdx.x & 63) == 0) s_red[threadIdx.x >> 6] = acc;
    __syncthreads();
    if (threadIdx.x == 0)
        atomicAdd(acc_mask, s_red[0] + s_red[1] + s_red[2] + s_red[3]);
}

// ---------------------------------------------------------------------------
// K8: finalize.
// ---------------------------------------------------------------------------
__global__ void k8_final(const float* __restrict__ acc, const int* __restrict__ npos,
                         float* __restrict__ out) {
    float denom = fmaxf((float)(*npos), 1.0f);
    out[0] = (1.0f * acc[0] + 1.5f * acc[1] + 6.125f * (acc[2] / (float)PHW)) / denom;
}

// ---------------------------------------------------------------------------
extern "C" void kernel_launch(void* const* d_in, const int* in_sizes, int n_in,
                              void* d_out, int out_size, void* d_ws, size_t ws_size,
                              hipStream_t stream) {
    (void)in_sizes; (void)n_in; (void)out_size; (void)ws_size;
    const float* class_preds = (const float*)d_in[0];
    const float* box_preds   = (const float*)d_in[1];
    const float* mask_coeffs = (const float*)d_in[2];
    const float* prototypes  = (const float*)d_in[3];
    const float* anchors     = (const float*)d_in[4];
    const float* gt_boxes    = (const float*)d_in[5];
    const int*   gt_labels   = (const int*)d_in[6];
    const float* gt_masks    = (const float*)d_in[7];
    float* out = (float*)d_out;

    size_t off = 0;
    char* w = (char*)d_ws;
    auto take = [&](size_t bytes) -> char* {
        char* p = w + off;
        off += (bytes + 255) & ~(size_t)255;
        return p;
    };
    float* acc      = (float*)take(32);                       // [cls, box, mask, npos(int)]
    float* best_iou = (float*)take((size_t)BB * AA * 4);
    int*   best_g   = (int*)  take((size_t)BB * AA * 4);
    int*   gidx     = (int*)  take((size_t)BB * AA * 4);
    int*   selmask  = (int*)  take((size_t)BB * AA * 4);
    int*   banchor  = (int*)  take((size_t)BB * GG * 4);
    int*   pos_cnt  = (int*)  take((size_t)BB * 4);
    unsigned long long* pos_key = (unsigned long long*)take((size_t)BB * AA * 8);
    int*   sel_g    = (int*)  take((size_t)BB * KPOS * 4);
    int*   sel_cnt  = (int*)  take((size_t)BB * 4);
    float* sel_coef = (float*)take((size_t)BB * KPOS * PP * 4);

    hipMemsetAsync(acc, 0, 32, stream);

    k1_best_per_anchor<<<dim3((AA + 255) / 256, BB), 256, 0, stream>>>(
        anchors, gt_boxes, best_iou, best_g);
    k2_best_anchor_per_gt<<<dim3(GG, BB), 256, 0, stream>>>(
        anchors, gt_boxes, banchor);
    k3_match_scan<<<BB, 1024, 0, stream>>>(
        best_iou, best_g, banchor, gidx, selmask, pos_key, pos_cnt, (int*)(acc + 3));
    k4_focal<<<(BB * AA) / 4, 256, 0, stream>>>(
        class_preds, gt_labels, gidx, selmask, acc + 0);
    k5_box<<<(BB * AA + 255) / 256, 256, 0, stream>>>(
        box_preds, anchors, gt_boxes, gidx, selmask, acc + 1);
    k6_select<<<BB, 1024, 0, stream>>>(
        pos_key, pos_cnt, gidx, mask_coeffs, sel_g, sel_coef, sel_cnt);
    k7_mask<<<dim3((PHW + 255) / 256, BB), 256, 0, stream>>>(
        prototypes, gt_masks, sel_coef, sel_g, sel_cnt, acc + 2);
    k8_final<<<1, 1, 0, stream>>>(acc, (int*)(acc + 3), out);
}

// Round 2
// 396.681 us; speedup vs baseline: 1.6816x; 1.6816x over previous
//
#include <hip/hip_runtime.h>
#include <math.h>

#define BB 8
#define AA 19248
#define GG 32
#define CC 81
#define PP 32
#define PHW 19044   /* 138*138 */
#define KPOS 128
#define NEGRATIO 3
#define SELCAP 7680

// ---------------------------------------------------------------------------
// IoU helper — contraction off so K1 and K2 produce bitwise-identical values
// and FMA fusion can't flip threshold/argmax decisions vs the XLA reference.
// ---------------------------------------------------------------------------
__device__ __forceinline__ float iou_one(float ax1, float ay1, float ax2, float ay2,
                                         float areaA,
                                         float gx1, float gy1, float gx2, float gy2) {
#pragma clang fp contract(off)
    float ix1 = fmaxf(ax1, gx1), iy1 = fmaxf(ay1, gy1);
    float ix2 = fminf(ax2, gx2), iy2 = fminf(ay2, gy2);
    float iw = fmaxf(ix2 - ix1, 0.0f), ih = fmaxf(iy2 - iy1, 0.0f);
    float inter = iw * ih;
    float areaB = (gx2 - gx1) * (gy2 - gy1);
    float u = areaA + areaB - inter;
    u = fmaxf(u, 1e-6f);
    return inter / u;
}

// ---------------------------------------------------------------------------
// K1: per (b,a) best IoU + first-max argmax over the 32 GT boxes.
// ---------------------------------------------------------------------------
__global__ void k1_best_per_anchor(const float* __restrict__ anchors,
                                   const float* __restrict__ gt_boxes,
                                   float* __restrict__ best_iou,
                                   int* __restrict__ best_g) {
#pragma clang fp contract(off)
    int b = blockIdx.y;
    int a = blockIdx.x * 256 + threadIdx.x;
    __shared__ float sg[GG][4];
    for (int t = threadIdx.x; t < GG * 4; t += 256)
        sg[t >> 2][t & 3] = gt_boxes[b * GG * 4 + t] / 550.0f;
    __syncthreads();
    if (a >= AA) return;
    float4 an = ((const float4*)anchors)[a];
    float ax1 = an.x - an.z * 0.5f, ay1 = an.y - an.w * 0.5f;
    float ax2 = an.x + an.z * 0.5f, ay2 = an.y + an.w * 0.5f;
    float areaA = (ax2 - ax1) * (ay2 - ay1);
    float best = -1.0f; int bi = 0;
    for (int g = 0; g < GG; ++g) {
        float v = iou_one(ax1, ay1, ax2, ay2, areaA, sg[g][0], sg[g][1], sg[g][2], sg[g][3]);
        if (v > best) { best = v; bi = g; }  // strict > keeps FIRST max (jnp.argmax)
    }
    best_iou[b * AA + a] = best;
    best_g[b * AA + a] = bi;
}

// ---------------------------------------------------------------------------
// K2: per (b,g) argmax over all anchors (first occurrence on ties -> packed
// key with inverted index, take max).
// ---------------------------------------------------------------------------
__global__ void k2_best_anchor_per_gt(const float* __restrict__ anchors,
                                      const float* __restrict__ gt_boxes,
                                      int* __restrict__ best_anchor) {
#pragma clang fp contract(off)
    int b = blockIdx.y, g = blockIdx.x;
    float gx1 = gt_boxes[(b * GG + g) * 4 + 0] / 550.0f;
    float gy1 = gt_boxes[(b * GG + g) * 4 + 1] / 550.0f;
    float gx2 = gt_boxes[(b * GG + g) * 4 + 2] / 550.0f;
    float gy2 = gt_boxes[(b * GG + g) * 4 + 3] / 550.0f;
    unsigned long long lk = 0ULL;
    const float4* a4 = (const float4*)anchors;
    for (int a = threadIdx.x; a < AA; a += 256) {
        float4 an = a4[a];
        float ax1 = an.x - an.z * 0.5f, ay1 = an.y - an.w * 0.5f;
        float ax2 = an.x + an.z * 0.5f, ay2 = an.y + an.w * 0.5f;
        float areaA = (ax2 - ax1) * (ay2 - ay1);
        float v = iou_one(ax1, ay1, ax2, ay2, areaA, gx1, gy1, gx2, gy2);
        unsigned long long key =
            ((unsigned long long)__float_as_uint(v) << 32) | (unsigned)(AA - 1 - a);
        if (key > lk) lk = key;
    }
    for (int off = 32; off; off >>= 1) {
        unsigned long long o = __shfl_xor(lk, off);
        if (o > lk) lk = o;
    }
    __shared__ unsigned long long sk[4];
    if ((threadIdx.x & 63) == 0) sk[threadIdx.x >> 6] = lk;
    __syncthreads();
    if (threadIdx.x == 0) {
        unsigned long long m = sk[0];
        for (int i = 1; i < 4; ++i) if (sk[i] > m) m = sk[i];
        best_anchor[b * GG + g] = AA - 1 - (int)(unsigned)(m & 0xffffffffu);
    }
}

// ---------------------------------------------------------------------------
// K3: per image — apply scatter overrides (pos=true, gidx=g, last/largest g
// wins on duplicates = XLA-CPU scatter order), count positives, compact
// positive keys for top-k, inclusive-scan the hard-negative mask and cap it,
// then compact all active (pos|selected-neg) anchor indices into act_list.
// selmask: 0 = unused, 1 = neg, 2 = pos.
// ---------------------------------------------------------------------------
__global__ __launch_bounds__(1024) void k3_match_scan(
    const float* __restrict__ best_iou, const int* __restrict__ best_g_in,
    const int* __restrict__ best_anchor,
    int* __restrict__ gidx_out, int* __restrict__ selmask,
    unsigned long long* __restrict__ pos_key,
    int* __restrict__ pos_cnt, int* __restrict__ g_npos,
    int* __restrict__ act_list, int* __restrict__ act_cnt) {
#pragma clang fp contract(off)
    int b = blockIdx.x;
    int tid = threadIdx.x;
    __shared__ int sba[GG];
    __shared__ int s_cnt;
    __shared__ int s_act;
    __shared__ int s_ws[16];
    __shared__ int s_tot;
    if (tid < GG) sba[tid] = best_anchor[b * GG + tid];
    if (tid == 0) { s_cnt = 0; s_act = 0; }
    __syncthreads();

    for (int a = tid; a < AA; a += 1024) {
        float biou = best_iou[b * AA + a];
        int gi = best_g_in[b * AA + a];
        bool p = (biou >= 0.5f);
        for (int g = 0; g < GG; ++g)
            if (sba[g] == a) { p = true; gi = g; }   // ascending -> last wins
        bool npre = (biou < 0.4f) && !p;
        gidx_out[b * AA + a] = gi;
        selmask[b * AA + a] = p ? 2 : (npre ? 1 : 0);
        if (p) {
            int slot = atomicAdd(&s_cnt, 1);
            unsigned long long key =
                ((unsigned long long)__float_as_uint(biou + 1.0f) << 32) |
                (unsigned)(AA - 1 - a);
            pos_key[(size_t)b * AA + slot] = key;
        }
    }
    __syncthreads();
    int npos = s_cnt;
    if (tid == 0) { pos_cnt[b] = npos; atomicAdd(g_npos, npos); }
    int cap = npos * NEGRATIO;

    // inclusive scan over neg-pre mask, drop entries beyond cap
    int lane = tid & 63, wid = tid >> 6;
    int running = 0;
    for (int base = 0; base < AA; base += 1024) {
        int a = base + tid;
        int v = 0;
        if (a < AA && selmask[b * AA + a] == 1) v = 1;
        int c = v;
        #pragma unroll
        for (int d = 1; d < 64; d <<= 1) {
            int t = __shfl_up(c, d);
            if (lane >= d) c += t;
        }
        if (lane == 63) s_ws[wid] = c;
        __syncthreads();
        if (tid == 0) {
            int run = 0;
            for (int i = 0; i < 16; ++i) { int t = s_ws[i]; s_ws[i] = run; run += t; }
            s_tot = run;
        }
        __syncthreads();
        int cum = running + s_ws[wid] + c;   // inclusive cumsum
        if (v && cum > cap) selmask[b * AA + a] = 0;
        running += s_tot;
        __syncthreads();
    }

    // compact active rows (order irrelevant: consumed by commutative sums)
    for (int a = tid; a < AA; a += 1024) {
        if (selmask[b * AA + a] != 0) {
            int slot = atomicAdd(&s_act, 1);
            act_list[b * AA + slot] = a;
        }
    }
    __syncthreads();
    if (tid == 0) act_cnt[b] = s_act;
}

// ---------------------------------------------------------------------------
// K4: focal classification loss over the compacted active list.
// One 64-lane group per row; per-block LDS reduction -> ONE atomic per block.
// ---------------------------------------------------------------------------
__global__ __launch_bounds__(256) void k4_focal(
    const float* __restrict__ cls_p, const int* __restrict__ gtl,
    const int* __restrict__ gidx, const int* __restrict__ selmask,
    const int* __restrict__ act_list, const int* __restrict__ act_cnt,
    float* __restrict__ acc_cls) {
    int b = blockIdx.y;
    int n = act_cnt[b];
    int group = blockIdx.x * 4 + (threadIdx.x >> 6);
    int lane = threadIdx.x & 63;
    float fsum = 0.0f;
    for (int i = group; i < n; i += 32 * 4) {
        int a = act_list[b * AA + i];
        int r = b * AA + a;
        const float* x = cls_p + (size_t)r * CC;
        float e0 = x[lane];
        float e1 = (lane < CC - 64) ? x[64 + lane] : -3.0e38f;
        float m = fmaxf(e0, e1);
        for (int off = 32; off; off >>= 1) m = fmaxf(m, __shfl_xor(m, off));
        float s = expf(e0 - m) + ((lane < CC - 64) ? expf(e1 - m) : 0.0f);
        for (int off = 32; off; off >>= 1) s += __shfl_xor(s, off);
        if (lane == 0) {
            int sm = selmask[r];
            int lbl = (sm == 2) ? gtl[b * GG + gidx[r]] : 0;
            float pt = expf(x[lbl] - m) / s;
            pt = fminf(fmaxf(pt, 1e-6f), 1.0f - 1e-6f);
            float at = (lbl > 0) ? 0.25f : 0.75f;
            float om = 1.0f - pt;
            fsum += at * om * om * (-logf(pt));
        }
    }
    __shared__ float s4[4];
    if (lane == 0) s4[threadIdx.x >> 6] = fsum;
    __syncthreads();
    if (threadIdx.x == 0) {
        float t = s4[0] + s4[1] + s4[2] + s4[3];
        atomicAdd(acc_cls, t);
    }
}

// ---------------------------------------------------------------------------
// K5: box regression loss (smooth L1), positives from the compacted list.
// Per-block reduction -> ONE atomic per block.
// ---------------------------------------------------------------------------
__global__ __launch_bounds__(256) void k5_box(
    const float* __restrict__ box_p, const float* __restrict__ anchors,
    const float* __restrict__ gt_boxes, const int* __restrict__ gidx,
    const int* __restrict__ selmask, const int* __restrict__ act_list,
    const int* __restrict__ act_cnt, float* __restrict__ acc_box) {
#pragma clang fp contract(off)
    int b = blockIdx.y;
    int n = act_cnt[b];
    float lsum = 0.0f;
    for (int i = blockIdx.x * 256 + threadIdx.x; i < n; i += 8 * 256) {
        int a = act_list[b * AA + i];
        int r = b * AA + a;
        if (selmask[r] != 2) continue;
        int g = gidx[r];
        float m0 = gt_boxes[(b * GG + g) * 4 + 0] / 550.0f;
        float m1 = gt_boxes[(b * GG + g) * 4 + 1] / 550.0f;
        float m2 = gt_boxes[(b * GG + g) * 4 + 2] / 550.0f;
        float m3 = gt_boxes[(b * GG + g) * 4 + 3] / 550.0f;
        float4 an = ((const float4*)anchors)[a];
        float gcx = 0.5f * (m0 + m2), gcy = 0.5f * (m1 + m3);
        float gw = fmaxf(m2 - m0, 1e-6f), gh = fmaxf(m3 - m1, 1e-6f);
        float t0 = (gcx - an.x) / (an.z * 0.1f);
        float t1 = (gcy - an.y) / (an.w * 0.1f);
        float t2 = logf(gw / an.z) / 0.2f;
        float t3 = logf(gh / an.w) / 0.2f;
        const float* bp = box_p + (size_t)r * 4;
        float d;
        d = fabsf(bp[0] - t0); lsum += (d < 1.0f) ? 0.5f * d * d : d - 0.5f;
        d = fabsf(bp[1] - t1); lsum += (d < 1.0f) ? 0.5f * d * d : d - 0.5f;
        d = fabsf(bp[2] - t2); lsum += (d < 1.0f) ? 0.5f * d * d : d - 0.5f;
        d = fabsf(bp[3] - t3); lsum += (d < 1.0f) ? 0.5f * d * d : d - 0.5f;
    }
    for (int off = 32; off; off >>= 1) lsum += __shfl_xor(lsum, off);
    __shared__ float s4[4];
    if ((threadIdx.x & 63) == 0) s4[threadIdx.x >> 6] = lsum;
    __syncthreads();
    if (threadIdx.x == 0) {
        float t = s4[0] + s4[1] + s4[2] + s4[3];
        atomicAdd(acc_box, t);
    }
}

// ---------------------------------------------------------------------------
// K6: per-image top-min(npos,128) selection by packed key (value desc, index
// asc) via repeated block-argmax over the compacted positive list (LDS-
// resident when it fits). Gathers selected coeffs + matched gt index.
// ---------------------------------------------------------------------------
__global__ __launch_bounds__(1024) void k6_select(
    unsigned long long* __restrict__ pos_key, const int* __restrict__ pos_cnt,
    const int* __restrict__ gidx, const float* __restrict__ coeffs,
    int* __restrict__ sel_g, float* __restrict__ sel_coef, int* __restrict__ sel_cnt) {
    int b = blockIdx.x, tid = threadIdx.x;
    __shared__ unsigned long long s_keys[SELCAP];
    __shared__ unsigned long long s_red[16];
    __shared__ unsigned long long s_max;
    __shared__ int s_sel_a[KPOS];
    int n = pos_cnt[b];
    bool use_lds = (n <= SELCAP);
    unsigned long long* keys;
    if (use_lds) {
        for (int i = tid; i < n; i += 1024) s_keys[i] = pos_key[(size_t)b * AA + i];
        keys = s_keys;
    } else {
        keys = pos_key + (size_t)b * AA;
    }
    __syncthreads();
    int lane = tid & 63, wid = tid >> 6;
    int rounds = (n < KPOS) ? n : KPOS;
    for (int r = 0; r < rounds; ++r) {
        unsigned long long lk = 0ULL;
        for (int i = tid; i < n; i += 1024) { unsigned long long k = keys[i]; if (k > lk) lk = k; }
        for (int off = 32; off; off >>= 1) {
            unsigned long long o = __shfl_xor(lk, off);
            if (o > lk) lk = o;
        }
        if (lane == 0) s_red[wid] = lk;
        __syncthreads();
        if (tid == 0) {
            unsigned long long m = 0ULL;
            for (int i = 0; i < 16; ++i) if (s_red[i] > m) m = s_red[i];
            s_max = m;
        }
        __syncthreads();
        unsigned long long m = s_max;
        if (tid == 0) s_sel_a[r] = AA - 1 - (int)(unsigned)(m & 0xffffffffu);
        for (int i = tid; i < n; i += 1024) if (keys[i] == m) keys[i] = 0ULL;  // unique
        __syncthreads();
    }
    if (tid == 0) sel_cnt[b] = rounds;
    __syncthreads();
    for (int t = tid; t < rounds * PP; t += 1024) {
        int k = t >> 5, p = t & 31;
        int a = s_sel_a[k];
        sel_coef[(b * KPOS + k) * PP + p] = coeffs[((size_t)(b * AA + a)) * PP + p];
    }
    for (int t = tid; t < rounds; t += 1024)
        sel_g[b * KPOS + t] = gidx[b * AA + s_sel_a[t]];
}

// ---------------------------------------------------------------------------
// K7: mask loss — logits = coeffs_sel(<=128 x 32) x protos(32 x 19044) + BCE,
// protos held in registers per pixel, coeffs in LDS, one pass over pixels.
// All selected entries have w=1 so sum raw BCE and divide by PHW at the end.
// ---------------------------------------------------------------------------
__global__ __launch_bounds__(256) void k7_mask(
    const float* __restrict__ protos, const float* __restrict__ gtm,
    const float* __restrict__ sel_coef, const int* __restrict__ sel_g,
    const int* __restrict__ sel_cnt, float* __restrict__ acc_mask) {
    int b = blockIdx.y;
    int pix = blockIdx.x * 256 + threadIdx.x;
    __shared__ float s_c[KPOS * PP];
    __shared__ int s_g[KPOS];
    __shared__ float s_red[4];
    int nk = sel_cnt[b];
    for (int t = threadIdx.x; t < nk * PP; t += 256) s_c[t] = sel_coef[b * KPOS * PP + t];
    for (int t = threadIdx.x; t < nk; t += 256) s_g[t] = sel_g[b * KPOS + t];
    __syncthreads();
    bool valid = pix < PHW;
    float pr[PP];
    #pragma unroll
    for (int p = 0; p < PP; ++p)
        pr[p] = valid ? protos[((size_t)(b * PP + p)) * PHW + pix] : 0.0f;
    float acc = 0.0f;
    for (int k = 0; k < nk; ++k) {
        const float* c = &s_c[k * PP];
        float l = 0.0f;
        #pragma unroll
        for (int p = 0; p < PP; ++p) l += c[p] * pr[p];
        float t = valid ? gtm[((size_t)(b * GG + s_g[k])) * PHW + pix] : 0.0f;
        float bce = fmaxf(l, 0.0f) - l * t + log1pf(expf(-fabsf(l)));
        if (valid) acc += bce;
    }
    for (int off = 32; off; off >>= 1) acc += __shfl_xor(acc, off);
    if ((threadIdx.x & 63) == 0) s_red[threadIdx.x >> 6] = acc;
    __syncthreads();
    if (threadIdx.x == 0)
        atomicAdd(acc_mask, s_red[0] + s_red[1] + s_red[2] + s_red[3]);
}

// ---------------------------------------------------------------------------
// K8: finalize.
// ---------------------------------------------------------------------------
__global__ void k8_final(const float* __restrict__ acc, const int* __restrict__ npos,
                         float* __restrict__ out) {
    float denom = fmaxf((float)(*npos), 1.0f);
    out[0] = (1.0f * acc[0] + 1.5f * acc[1] + 6.125f * (acc[2] / (float)PHW)) / denom;
}

// ---------------------------------------------------------------------------
extern "C" void kernel_launch(void* const* d_in, const int* in_sizes, int n_in,
                              void* d_out, int out_size, void* d_ws, size_t ws_size,
                              hipStream_t stream) {
    (void)in_sizes; (void)n_in; (void)out_size; (void)ws_size;
    const float* class_preds = (const float*)d_in[0];
    const float* box_preds   = (const float*)d_in[1];
    const float* mask_coeffs = (const float*)d_in[2];
    const float* prototypes  = (const float*)d_in[3];
    const float* anchors     = (const float*)d_in[4];
    const float* gt_boxes    = (const float*)d_in[5];
    const int*   gt_labels   = (const int*)d_in[6];
    const float* gt_masks    = (const float*)d_in[7];
    float* out = (float*)d_out;

    size_t off = 0;
    char* w = (char*)d_ws;
    auto take = [&](size_t bytes) -> char* {
        char* p = w + off;
        off += (bytes + 255) & ~(size_t)255;
        return p;
    };
    float* acc      = (float*)take(32);                       // [cls, box, mask, npos(int)]
    float* best_iou = (float*)take((size_t)BB * AA * 4);
    int*   best_g   = (int*)  take((size_t)BB * AA * 4);
    int*   gidx     = (int*)  take((size_t)BB * AA * 4);
    int*   selmask  = (int*)  take((size_t)BB * AA * 4);
    int*   banchor  = (int*)  take((size_t)BB * GG * 4);
    int*   pos_cnt  = (int*)  take((size_t)BB * 4);
    unsigned long long* pos_key = (unsigned long long*)take((size_t)BB * AA * 8);
    int*   sel_g    = (int*)  take((size_t)BB * KPOS * 4);
    int*   sel_cnt  = (int*)  take((size_t)BB * 4);
    float* sel_coef = (float*)take((size_t)BB * KPOS * PP * 4);
    int*   act_list = (int*)  take((size_t)BB * AA * 4);
    int*   act_cnt  = (int*)  take((size_t)BB * 4);

    hipMemsetAsync(acc, 0, 32, stream);

    k1_best_per_anchor<<<dim3((AA + 255) / 256, BB), 256, 0, stream>>>(
        anchors, gt_boxes, best_iou, best_g);
    k2_best_anchor_per_gt<<<dim3(GG, BB), 256, 0, stream>>>(
        anchors, gt_boxes, banchor);
    k3_match_scan<<<BB, 1024, 0, stream>>>(
        best_iou, best_g, banchor, gidx, selmask, pos_key, pos_cnt, (int*)(acc + 3),
        act_list, act_cnt);
    k4_focal<<<dim3(32, BB), 256, 0, stream>>>(
        class_preds, gt_labels, gidx, selmask, act_list, act_cnt, acc + 0);
    k5_box<<<dim3(8, BB), 256, 0, stream>>>(
        box_preds, anchors, gt_boxes, gidx, selmask, act_list, act_cnt, acc + 1);
    k6_select<<<BB, 1024, 0, stream>>>(
        pos_key, pos_cnt, gidx, mask_coeffs, sel_g, sel_coef, sel_cnt);
    k7_mask<<<dim3((PHW + 255) / 256, BB), 256, 0, stream>>>(
        prototypes, gt_masks, sel_coef, sel_g, sel_cnt, acc + 2);
    k8_final<<<1, 1, 0, stream>>>(acc, (int*)(acc + 3), out);
}

// Round 3
// 251.578 us; speedup vs baseline: 2.6514x; 1.5768x over previous
//
#include <hip/hip_runtime.h>
#include <math.h>

#define BB 8
#define AA 19248
#define GG 32
#define CC 81
#define PP 32
#define PHW 19044   /* 138*138 */
#define KPOS 128
#define NEGRATIO 3
#define SELCAP 7680

// ---------------------------------------------------------------------------
// IoU helper — contraction off so K1 and K2 produce bitwise-identical values
// and FMA fusion can't flip threshold/argmax decisions vs the XLA reference.
// ---------------------------------------------------------------------------
__device__ __forceinline__ float iou_one(float ax1, float ay1, float ax2, float ay2,
                                         float areaA,
                                         float gx1, float gy1, float gx2, float gy2) {
#pragma clang fp contract(off)
    float ix1 = fmaxf(ax1, gx1), iy1 = fmaxf(ay1, gy1);
    float ix2 = fminf(ax2, gx2), iy2 = fminf(ay2, gy2);
    float iw = fmaxf(ix2 - ix1, 0.0f), ih = fmaxf(iy2 - iy1, 0.0f);
    float inter = iw * ih;
    float areaB = (gx2 - gx1) * (gy2 - gy1);
    float u = areaA + areaB - inter;
    u = fmaxf(u, 1e-6f);
    return inter / u;
}

// ---------------------------------------------------------------------------
// K1: per (b,a) best IoU + first-max argmax over the 32 GT boxes.
// ---------------------------------------------------------------------------
__global__ void k1_best_per_anchor(const float* __restrict__ anchors,
                                   const float* __restrict__ gt_boxes,
                                   float* __restrict__ best_iou,
                                   int* __restrict__ best_g) {
#pragma clang fp contract(off)
    int b = blockIdx.y;
    int a = blockIdx.x * 256 + threadIdx.x;
    __shared__ float sg[GG][4];
    for (int t = threadIdx.x; t < GG * 4; t += 256)
        sg[t >> 2][t & 3] = gt_boxes[b * GG * 4 + t] / 550.0f;
    __syncthreads();
    if (a >= AA) return;
    float4 an = ((const float4*)anchors)[a];
    float ax1 = an.x - an.z * 0.5f, ay1 = an.y - an.w * 0.5f;
    float ax2 = an.x + an.z * 0.5f, ay2 = an.y + an.w * 0.5f;
    float areaA = (ax2 - ax1) * (ay2 - ay1);
    float best = -1.0f; int bi = 0;
    for (int g = 0; g < GG; ++g) {
        float v = iou_one(ax1, ay1, ax2, ay2, areaA, sg[g][0], sg[g][1], sg[g][2], sg[g][3]);
        if (v > best) { best = v; bi = g; }  // strict > keeps FIRST max (jnp.argmax)
    }
    best_iou[b * AA + a] = best;
    best_g[b * AA + a] = bi;
}

// ---------------------------------------------------------------------------
// K2: per (b,g) argmax over all anchors (first occurrence on ties -> packed
// key with inverted index, take max).
// ---------------------------------------------------------------------------
__global__ void k2_best_anchor_per_gt(const float* __restrict__ anchors,
                                      const float* __restrict__ gt_boxes,
                                      int* __restrict__ best_anchor) {
#pragma clang fp contract(off)
    int b = blockIdx.y, g = blockIdx.x;
    float gx1 = gt_boxes[(b * GG + g) * 4 + 0] / 550.0f;
    float gy1 = gt_boxes[(b * GG + g) * 4 + 1] / 550.0f;
    float gx2 = gt_boxes[(b * GG + g) * 4 + 2] / 550.0f;
    float gy2 = gt_boxes[(b * GG + g) * 4 + 3] / 550.0f;
    unsigned long long lk = 0ULL;
    const float4* a4 = (const float4*)anchors;
    for (int a = threadIdx.x; a < AA; a += 256) {
        float4 an = a4[a];
        float ax1 = an.x - an.z * 0.5f, ay1 = an.y - an.w * 0.5f;
        float ax2 = an.x + an.z * 0.5f, ay2 = an.y + an.w * 0.5f;
        float areaA = (ax2 - ax1) * (ay2 - ay1);
        float v = iou_one(ax1, ay1, ax2, ay2, areaA, gx1, gy1, gx2, gy2);
        unsigned long long key =
            ((unsigned long long)__float_as_uint(v) << 32) | (unsigned)(AA - 1 - a);
        if (key > lk) lk = key;
    }
    for (int off = 32; off; off >>= 1) {
        unsigned long long o = __shfl_xor(lk, off);
        if (o > lk) lk = o;
    }
    __shared__ unsigned long long sk[4];
    if ((threadIdx.x & 63) == 0) sk[threadIdx.x >> 6] = lk;
    __syncthreads();
    if (threadIdx.x == 0) {
        unsigned long long m = sk[0];
        for (int i = 1; i < 4; ++i) if (sk[i] > m) m = sk[i];
        best_anchor[b * GG + g] = AA - 1 - (int)(unsigned)(m & 0xffffffffu);
    }
}

// ---------------------------------------------------------------------------
// K3: per image — apply scatter overrides (pos=true, gidx=g, last/largest g
// wins on duplicates = XLA-CPU scatter order), count positives, compact
// positive keys for top-k, inclusive-scan the hard-negative mask and cap it,
// then compact all active (pos|selected-neg) anchor indices into act_list.
// selmask: 0 = unused, 1 = neg, 2 = pos.
// pos_key is a rebased, order-preserving 56-bit key:
//   ((bits(biou+1)-0x3F800000) << 32) | (AA-1-a)   — unique per anchor.
// ---------------------------------------------------------------------------
__global__ __launch_bounds__(1024) void k3_match_scan(
    const float* __restrict__ best_iou, const int* __restrict__ best_g_in,
    const int* __restrict__ best_anchor,
    int* __restrict__ gidx_out, int* __restrict__ selmask,
    unsigned long long* __restrict__ pos_key,
    int* __restrict__ pos_cnt, int* __restrict__ g_npos,
    int* __restrict__ act_list, int* __restrict__ act_cnt) {
#pragma clang fp contract(off)
    int b = blockIdx.x;
    int tid = threadIdx.x;
    __shared__ int sba[GG];
    __shared__ int s_cnt;
    __shared__ int s_act;
    __shared__ int s_ws[16];
    __shared__ int s_tot;
    if (tid < GG) sba[tid] = best_anchor[b * GG + tid];
    if (tid == 0) { s_cnt = 0; s_act = 0; }
    __syncthreads();

    for (int a = tid; a < AA; a += 1024) {
        float biou = best_iou[b * AA + a];
        int gi = best_g_in[b * AA + a];
        bool p = (biou >= 0.5f);
        for (int g = 0; g < GG; ++g)
            if (sba[g] == a) { p = true; gi = g; }   // ascending -> last wins
        bool npre = (biou < 0.4f) && !p;
        gidx_out[b * AA + a] = gi;
        selmask[b * AA + a] = p ? 2 : (npre ? 1 : 0);
        if (p) {
            int slot = atomicAdd(&s_cnt, 1);
            unsigned vb = __float_as_uint(biou + 1.0f);   // >= 0x3F800000 always
            unsigned long long key =
                ((unsigned long long)(vb - 0x3F800000u) << 32) |
                (unsigned)(AA - 1 - a);
            pos_key[(size_t)b * AA + slot] = key;
        }
    }
    __syncthreads();
    int npos = s_cnt;
    if (tid == 0) { pos_cnt[b] = npos; atomicAdd(g_npos, npos); }
    int cap = npos * NEGRATIO;

    // inclusive scan over neg-pre mask, drop entries beyond cap
    int lane = tid & 63, wid = tid >> 6;
    int running = 0;
    for (int base = 0; base < AA; base += 1024) {
        int a = base + tid;
        int v = 0;
        if (a < AA && selmask[b * AA + a] == 1) v = 1;
        int c = v;
        #pragma unroll
        for (int d = 1; d < 64; d <<= 1) {
            int t = __shfl_up(c, d);
            if (lane >= d) c += t;
        }
        if (lane == 63) s_ws[wid] = c;
        __syncthreads();
        if (tid == 0) {
            int run = 0;
            for (int i = 0; i < 16; ++i) { int t = s_ws[i]; s_ws[i] = run; run += t; }
            s_tot = run;
        }
        __syncthreads();
        int cum = running + s_ws[wid] + c;   // inclusive cumsum
        if (v && cum > cap) selmask[b * AA + a] = 0;
        running += s_tot;
        __syncthreads();
    }

    // compact active rows (order irrelevant: consumed by commutative sums)
    for (int a = tid; a < AA; a += 1024) {
        if (selmask[b * AA + a] != 0) {
            int slot = atomicAdd(&s_act, 1);
            act_list[b * AA + slot] = a;
        }
    }
    __syncthreads();
    if (tid == 0) act_cnt[b] = s_act;
}

// ---------------------------------------------------------------------------
// K4: focal classification loss over the compacted active list.
// One 64-lane group per row; per-block LDS reduction -> ONE atomic per block.
// ---------------------------------------------------------------------------
__global__ __launch_bounds__(256) void k4_focal(
    const float* __restrict__ cls_p, const int* __restrict__ gtl,
    const int* __restrict__ gidx, const int* __restrict__ selmask,
    const int* __restrict__ act_list, const int* __restrict__ act_cnt,
    float* __restrict__ acc_cls) {
    int b = blockIdx.y;
    int n = act_cnt[b];
    int group = blockIdx.x * 4 + (threadIdx.x >> 6);
    int lane = threadIdx.x & 63;
    float fsum = 0.0f;
    for (int i = group; i < n; i += 32 * 4) {
        int a = act_list[b * AA + i];
        int r = b * AA + a;
        const float* x = cls_p + (size_t)r * CC;
        float e0 = x[lane];
        float e1 = (lane < CC - 64) ? x[64 + lane] : -3.0e38f;
        float m = fmaxf(e0, e1);
        for (int off = 32; off; off >>= 1) m = fmaxf(m, __shfl_xor(m, off));
        float s = expf(e0 - m) + ((lane < CC - 64) ? expf(e1 - m) : 0.0f);
        for (int off = 32; off; off >>= 1) s += __shfl_xor(s, off);
        if (lane == 0) {
            int sm = selmask[r];
            int lbl = (sm == 2) ? gtl[b * GG + gidx[r]] : 0;
            float pt = expf(x[lbl] - m) / s;
            pt = fminf(fmaxf(pt, 1e-6f), 1.0f - 1e-6f);
            float at = (lbl > 0) ? 0.25f : 0.75f;
            float om = 1.0f - pt;
            fsum += at * om * om * (-logf(pt));
        }
    }
    __shared__ float s4[4];
    if (lane == 0) s4[threadIdx.x >> 6] = fsum;
    __syncthreads();
    if (threadIdx.x == 0) {
        float t = s4[0] + s4[1] + s4[2] + s4[3];
        atomicAdd(acc_cls, t);
    }
}

// ---------------------------------------------------------------------------
// K5: box regression loss (smooth L1), positives from the compacted list.
// Per-block reduction -> ONE atomic per block.
// ---------------------------------------------------------------------------
__global__ __launch_bounds__(256) void k5_box(
    const float* __restrict__ box_p, const float* __restrict__ anchors,
    const float* __restrict__ gt_boxes, const int* __restrict__ gidx,
    const int* __restrict__ selmask, const int* __restrict__ act_list,
    const int* __restrict__ act_cnt, float* __restrict__ acc_box) {
#pragma clang fp contract(off)
    int b = blockIdx.y;
    int n = act_cnt[b];
    float lsum = 0.0f;
    for (int i = blockIdx.x * 256 + threadIdx.x; i < n; i += 8 * 256) {
        int a = act_list[b * AA + i];
        int r = b * AA + a;
        if (selmask[r] != 2) continue;
        int g = gidx[r];
        float m0 = gt_boxes[(b * GG + g) * 4 + 0] / 550.0f;
        float m1 = gt_boxes[(b * GG + g) * 4 + 1] / 550.0f;
        float m2 = gt_boxes[(b * GG + g) * 4 + 2] / 550.0f;
        float m3 = gt_boxes[(b * GG + g) * 4 + 3] / 550.0f;
        float4 an = ((const float4*)anchors)[a];
        float gcx = 0.5f * (m0 + m2), gcy = 0.5f * (m1 + m3);
        float gw = fmaxf(m2 - m0, 1e-6f), gh = fmaxf(m3 - m1, 1e-6f);
        float t0 = (gcx - an.x) / (an.z * 0.1f);
        float t1 = (gcy - an.y) / (an.w * 0.1f);
        float t2 = logf(gw / an.z) / 0.2f;
        float t3 = logf(gh / an.w) / 0.2f;
        const float* bp = box_p + (size_t)r * 4;
        float d;
        d = fabsf(bp[0] - t0); lsum += (d < 1.0f) ? 0.5f * d * d : d - 0.5f;
        d = fabsf(bp[1] - t1); lsum += (d < 1.0f) ? 0.5f * d * d : d - 0.5f;
        d = fabsf(bp[2] - t2); lsum += (d < 1.0f) ? 0.5f * d * d : d - 0.5f;
        d = fabsf(bp[3] - t3); lsum += (d < 1.0f) ? 0.5f * d * d : d - 0.5f;
    }
    for (int off = 32; off; off >>= 1) lsum += __shfl_xor(lsum, off);
    __shared__ float s4[4];
    if ((threadIdx.x & 63) == 0) s4[threadIdx.x >> 6] = lsum;
    __syncthreads();
    if (threadIdx.x == 0) {
        float t = s4[0] + s4[1] + s4[2] + s4[3];
        atomicAdd(acc_box, t);
    }
}

// ---------------------------------------------------------------------------
// K6: per-image top-min(npos,128) selection via MSB-first radix select on the
// unique 56-bit keys (exact: T = K-th largest key; select {key >= T}).
// 7 byte-passes: LDS histogram + wave-parallel suffix scan, then one
// compaction pass. O(n) total, ~35 barriers, no serial 256-loops.
// ---------------------------------------------------------------------------
__global__ __launch_bounds__(1024) void k6_select(
    const unsigned long long* __restrict__ pos_key, const int* __restrict__ pos_cnt,
    const int* __restrict__ gidx, const float* __restrict__ coeffs,
    int* __restrict__ sel_g, float* __restrict__ sel_coef, int* __restrict__ sel_cnt) {
    int b = blockIdx.x, tid = threadIdx.x;
    __shared__ unsigned long long s_keys[SELCAP];
    __shared__ int s_hist[256];
    __shared__ int s_sfx[256];
    __shared__ int s_wsum[4];
    __shared__ unsigned long long s_prefix;
    __shared__ int s_kk;
    __shared__ int s_nsel;
    __shared__ int s_sel_a[KPOS];

    int n = pos_cnt[b];
    int K = (n < KPOS) ? n : KPOS;
    const unsigned long long* keys;
    if (n <= SELCAP) {
        for (int i = tid; i < n; i += 1024) s_keys[i] = pos_key[(size_t)b * AA + i];
        keys = s_keys;
    } else {
        keys = pos_key + (size_t)b * AA;
    }
    if (tid == 0) { s_prefix = 0ULL; s_kk = KPOS; s_nsel = 0; }
    __syncthreads();

    if (n > KPOS) {
        for (int d = 6; d >= 0; --d) {
            unsigned long long pref = s_prefix;   // snapshot (post-barrier)
            int kk = s_kk;
            if (tid < 256) s_hist[tid] = 0;
            __syncthreads();
            unsigned long long mhi = ~((1ULL << (8 * (d + 1))) - 1ULL);
            for (int i = tid; i < n; i += 1024) {
                unsigned long long k = keys[i];
                if ((k & mhi) == pref)
                    atomicAdd(&s_hist[(int)((k >> (8 * d)) & 255)], 1);
            }
            __syncthreads();
            // suffix sums: s_sfx[v] = #candidates with digit >= v
            int x = 0;
            if (tid < 256) {
                x = s_hist[255 - tid];
                #pragma unroll
                for (int o = 1; o < 64; o <<= 1) {
                    int t = __shfl_up(x, o);
                    if ((tid & 63) >= o) x += t;
                }
                if ((tid & 63) == 63) s_wsum[tid >> 6] = x;
            }
            __syncthreads();
            if (tid == 0) {
                int run = 0;
                #pragma unroll
                for (int i = 0; i < 4; ++i) { int t = s_wsum[i]; s_wsum[i] = run; run += t; }
            }
            __syncthreads();
            if (tid < 256) s_sfx[255 - tid] = x + s_wsum[tid >> 6];
            __syncthreads();
            if (tid < 256) {
                int v = tid;
                int ge = s_sfx[v];
                int gt = (v == 255) ? 0 : s_sfx[v + 1];
                if (ge >= kk && gt < kk) {          // exactly one v
                    s_prefix = pref | ((unsigned long long)v << (8 * d));
                    s_kk = kk - gt;
                }
            }
            __syncthreads();
        }
    }

    unsigned long long T = (n > KPOS) ? s_prefix : 0ULL;
    for (int i = tid; i < n; i += 1024) {
        unsigned long long k = keys[i];
        if (k >= T) {
            int slot = atomicAdd(&s_nsel, 1);
            if (slot < KPOS)
                s_sel_a[slot] = AA - 1 - (int)(unsigned)(k & 0xffffffffu);
        }
    }
    __syncthreads();

    if (tid == 0) sel_cnt[b] = K;
    for (int t = tid; t < K * PP; t += 1024) {
        int k = t >> 5, p = t & 31;
        int a = s_sel_a[k];
        sel_coef[(b * KPOS + k) * PP + p] = coeffs[((size_t)(b * AA + a)) * PP + p];
    }
    for (int t = tid; t < K; t += 1024)
        sel_g[b * KPOS + t] = gidx[b * AA + s_sel_a[t]];
}

// ---------------------------------------------------------------------------
// K7: mask loss — logits = coeffs_sel(<=128 x 32) x protos(32 x 19044) + BCE,
// protos held in registers per pixel, coeffs in LDS, one pass over pixels.
// All selected entries have w=1 so sum raw BCE and divide by PHW at the end.
// ---------------------------------------------------------------------------
__global__ __launch_bounds__(256) void k7_mask(
    const float* __restrict__ protos, const float* __restrict__ gtm,
    const float* __restrict__ sel_coef, const int* __restrict__ sel_g,
    const int* __restrict__ sel_cnt, float* __restrict__ acc_mask) {
    int b = blockIdx.y;
    int pix = blockIdx.x * 256 + threadIdx.x;
    __shared__ float s_c[KPOS * PP];
    __shared__ int s_g[KPOS];
    __shared__ float s_red[4];
    int nk = sel_cnt[b];
    for (int t = threadIdx.x; t < nk * PP; t += 256) s_c[t] = sel_coef[b * KPOS * PP + t];
    for (int t = threadIdx.x; t < nk; t += 256) s_g[t] = sel_g[b * KPOS + t];
    __syncthreads();
    bool valid = pix < PHW;
    float pr[PP];
    #pragma unroll
    for (int p = 0; p < PP; ++p)
        pr[p] = valid ? protos[((size_t)(b * PP + p)) * PHW + pix] : 0.0f;
    float acc = 0.0f;
    for (int k = 0; k < nk; ++k) {
        const float* c = &s_c[k * PP];
        float l = 0.0f;
        #pragma unroll
        for (int p = 0; p < PP; ++p) l += c[p] * pr[p];
        float t = valid ? gtm[((size_t)(b * GG + s_g[k])) * PHW + pix] : 0.0f;
        float bce = fmaxf(l, 0.0f) - l * t + log1pf(expf(-fabsf(l)));
        if (valid) acc += bce;
    }
    for (int off = 32; off; off >>= 1) acc += __shfl_xor(acc, off);
    if ((threadIdx.x & 63) == 0) s_red[threadIdx.x >> 6] = acc;
    __syncthreads();
    if (threadIdx.x == 0)
        atomicAdd(acc_mask, s_red[0] + s_red[1] + s_red[2] + s_red[3]);
}

// ---------------------------------------------------------------------------
// K8: finalize.
// ---------------------------------------------------------------------------
__global__ void k8_final(const float* __restrict__ acc, const int* __restrict__ npos,
                         float* __restrict__ out) {
    float denom = fmaxf((float)(*npos), 1.0f);
    out[0] = (1.0f * acc[0] + 1.5f * acc[1] + 6.125f * (acc[2] / (float)PHW)) / denom;
}

// ---------------------------------------------------------------------------
extern "C" void kernel_launch(void* const* d_in, const int* in_sizes, int n_in,
                              void* d_out, int out_size, void* d_ws, size_t ws_size,
                              hipStream_t stream) {
    (void)in_sizes; (void)n_in; (void)out_size; (void)ws_size;
    const float* class_preds = (const float*)d_in[0];
    const float* box_preds   = (const float*)d_in[1];
    const float* mask_coeffs = (const float*)d_in[2];
    const float* prototypes  = (const float*)d_in[3];
    const float* anchors     = (const float*)d_in[4];
    const float* gt_boxes    = (const float*)d_in[5];
    const int*   gt_labels   = (const int*)d_in[6];
    const float* gt_masks    = (const float*)d_in[7];
    float* out = (float*)d_out;

    size_t off = 0;
    char* w = (char*)d_ws;
    auto take = [&](size_t bytes) -> char* {
        char* p = w + off;
        off += (bytes + 255) & ~(size_t)255;
        return p;
    };
    float* acc      = (float*)take(32);                       // [cls, box, mask, npos(int)]
    float* best_iou = (float*)take((size_t)BB * AA * 4);
    int*   best_g   = (int*)  take((size_t)BB * AA * 4);
    int*   gidx     = (int*)  take((size_t)BB * AA * 4);
    int*   selmask  = (int*)  take((size_t)BB * AA * 4);
    int*   banchor  = (int*)  take((size_t)BB * GG * 4);
    int*   pos_cnt  = (int*)  take((size_t)BB * 4);
    unsigned long long* pos_key = (unsigned long long*)take((size_t)BB * AA * 8);
    int*   sel_g    = (int*)  take((size_t)BB * KPOS * 4);
    int*   sel_cnt  = (int*)  take((size_t)BB * 4);
    float* sel_coef = (float*)take((size_t)BB * KPOS * PP * 4);
    int*   act_list = (int*)  take((size_t)BB * AA * 4);
    int*   act_cnt  = (int*)  take((size_t)BB * 4);

    hipMemsetAsync(acc, 0, 32, stream);

    k1_best_per_anchor<<<dim3((AA + 255) / 256, BB), 256, 0, stream>>>(
        anchors, gt_boxes, best_iou, best_g);
    k2_best_anchor_per_gt<<<dim3(GG, BB), 256, 0, stream>>>(
        anchors, gt_boxes, banchor);
    k3_match_scan<<<BB, 1024, 0, stream>>>(
        best_iou, best_g, banchor, gidx, selmask, pos_key, pos_cnt, (int*)(acc + 3),
        act_list, act_cnt);
    k4_focal<<<dim3(32, BB), 256, 0, stream>>>(
        class_preds, gt_labels, gidx, selmask, act_list, act_cnt, acc + 0);
    k5_box<<<dim3(8, BB), 256, 0, stream>>>(
        box_preds, anchors, gt_boxes, gidx, selmask, act_list, act_cnt, acc + 1);
    k6_select<<<BB, 1024, 0, stream>>>(
        pos_key, pos_cnt, gidx, mask_coeffs, sel_g, sel_coef, sel_cnt);
    k7_mask<<<dim3((PHW + 255) / 256, BB), 256, 0, stream>>>(
        prototypes, gt_masks, sel_coef, sel_g, sel_cnt, acc + 2);
    k8_final<<<1, 1, 0, stream>>>(acc, (int*)(acc + 3), out);
}

// Round 4
// 192.065 us; speedup vs baseline: 3.4730x; 1.3099x over previous
//
#include <hip/hip_runtime.h>
#include <math.h>

#define BB 8
#define AA 19248
#define GG 32
#define CC 81
#define PP 32
#define PHW 19044   /* 138*138 */
#define KPOS 128
#define NEGRATIO 3
#define SELCAP 7680

// ---------------------------------------------------------------------------
// IoU helper — contraction off so K1 and K2 produce bitwise-identical values
// and FMA fusion can't flip threshold/argmax decisions vs the XLA reference.
// ---------------------------------------------------------------------------
__device__ __forceinline__ float iou_one(float ax1, float ay1, float ax2, float ay2,
                                         float areaA,
                                         float gx1, float gy1, float gx2, float gy2) {
#pragma clang fp contract(off)
    float ix1 = fmaxf(ax1, gx1), iy1 = fmaxf(ay1, gy1);
    float ix2 = fminf(ax2, gx2), iy2 = fminf(ay2, gy2);
    float iw = fmaxf(ix2 - ix1, 0.0f), ih = fmaxf(iy2 - iy1, 0.0f);
    float inter = iw * ih;
    float areaB = (gx2 - gx1) * (gy2 - gy1);
    float u = areaA + areaB - inter;
    u = fmaxf(u, 1e-6f);
    return inter / u;
}

// ---------------------------------------------------------------------------
// K1: per (b,a) best IoU + first-max argmax over the 32 GT boxes.
// ---------------------------------------------------------------------------
__global__ void k1_best_per_anchor(const float* __restrict__ anchors,
                                   const float* __restrict__ gt_boxes,
                                   float* __restrict__ best_iou,
                                   int* __restrict__ best_g) {
#pragma clang fp contract(off)
    int b = blockIdx.y;
    int a = blockIdx.x * 256 + threadIdx.x;
    __shared__ float sg[GG][4];
    for (int t = threadIdx.x; t < GG * 4; t += 256)
        sg[t >> 2][t & 3] = gt_boxes[b * GG * 4 + t] / 550.0f;
    __syncthreads();
    if (a >= AA) return;
    float4 an = ((const float4*)anchors)[a];
    float ax1 = an.x - an.z * 0.5f, ay1 = an.y - an.w * 0.5f;
    float ax2 = an.x + an.z * 0.5f, ay2 = an.y + an.w * 0.5f;
    float areaA = (ax2 - ax1) * (ay2 - ay1);
    float best = -1.0f; int bi = 0;
    for (int g = 0; g < GG; ++g) {
        float v = iou_one(ax1, ay1, ax2, ay2, areaA, sg[g][0], sg[g][1], sg[g][2], sg[g][3]);
        if (v > best) { best = v; bi = g; }  // strict > keeps FIRST max (jnp.argmax)
    }
    best_iou[b * AA + a] = best;
    best_g[b * AA + a] = bi;
}

// ---------------------------------------------------------------------------
// K2: per (b,g) argmax over all anchors (first occurrence on ties -> packed
// key with inverted index, take max).
// ---------------------------------------------------------------------------
__global__ void k2_best_anchor_per_gt(const float* __restrict__ anchors,
                                      const float* __restrict__ gt_boxes,
                                      int* __restrict__ best_anchor) {
#pragma clang fp contract(off)
    int b = blockIdx.y, g = blockIdx.x;
    float gx1 = gt_boxes[(b * GG + g) * 4 + 0] / 550.0f;
    float gy1 = gt_boxes[(b * GG + g) * 4 + 1] / 550.0f;
    float gx2 = gt_boxes[(b * GG + g) * 4 + 2] / 550.0f;
    float gy2 = gt_boxes[(b * GG + g) * 4 + 3] / 550.0f;
    unsigned long long lk = 0ULL;
    const float4* a4 = (const float4*)anchors;
    for (int a = threadIdx.x; a < AA; a += 256) {
        float4 an = a4[a];
        float ax1 = an.x - an.z * 0.5f, ay1 = an.y - an.w * 0.5f;
        float ax2 = an.x + an.z * 0.5f, ay2 = an.y + an.w * 0.5f;
        float areaA = (ax2 - ax1) * (ay2 - ay1);
        float v = iou_one(ax1, ay1, ax2, ay2, areaA, gx1, gy1, gx2, gy2);
        unsigned long long key =
            ((unsigned long long)__float_as_uint(v) << 32) | (unsigned)(AA - 1 - a);
        if (key > lk) lk = key;
    }
    for (int off = 32; off; off >>= 1) {
        unsigned long long o = __shfl_xor(lk, off);
        if (o > lk) lk = o;
    }
    __shared__ unsigned long long sk[4];
    if ((threadIdx.x & 63) == 0) sk[threadIdx.x >> 6] = lk;
    __syncthreads();
    if (threadIdx.x == 0) {
        unsigned long long m = sk[0];
        for (int i = 1; i < 4; ++i) if (sk[i] > m) m = sk[i];
        best_anchor[b * GG + g] = AA - 1 - (int)(unsigned)(m & 0xffffffffu);
    }
}

// ---------------------------------------------------------------------------
// K3: per image — apply scatter overrides (pos=true, gidx=g, last/largest g
// wins on duplicates = XLA-CPU scatter order), count positives, compact
// positive keys for top-k, inclusive-scan the hard-negative mask and cap it,
// then compact all active (pos|selected-neg) anchor indices into act_list.
// selmask: 0 = unused, 1 = neg, 2 = pos.
// pos_key is a rebased, order-preserving 56-bit key:
//   ((bits(biou+1)-0x3F800000) << 32) | (AA-1-a)   — unique per anchor.
// ---------------------------------------------------------------------------
__global__ __launch_bounds__(1024) void k3_match_scan(
    const float* __restrict__ best_iou, const int* __restrict__ best_g_in,
    const int* __restrict__ best_anchor,
    int* __restrict__ gidx_out, int* __restrict__ selmask,
    unsigned long long* __restrict__ pos_key,
    int* __restrict__ pos_cnt, int* __restrict__ g_npos,
    int* __restrict__ act_list, int* __restrict__ act_cnt) {
#pragma clang fp contract(off)
    int b = blockIdx.x;
    int tid = threadIdx.x;
    __shared__ int sba[GG];
    __shared__ int s_cnt;
    __shared__ int s_act;
    __shared__ int s_ws[16];
    __shared__ int s_tot;
    if (tid < GG) sba[tid] = best_anchor[b * GG + tid];
    if (tid == 0) { s_cnt = 0; s_act = 0; }
    __syncthreads();

    for (int a = tid; a < AA; a += 1024) {
        float biou = best_iou[b * AA + a];
        int gi = best_g_in[b * AA + a];
        bool p = (biou >= 0.5f);
        for (int g = 0; g < GG; ++g)
            if (sba[g] == a) { p = true; gi = g; }   // ascending -> last wins
        bool npre = (biou < 0.4f) && !p;
        gidx_out[b * AA + a] = gi;
        selmask[b * AA + a] = p ? 2 : (npre ? 1 : 0);
        if (p) {
            int slot = atomicAdd(&s_cnt, 1);
            unsigned vb = __float_as_uint(biou + 1.0f);   // >= 0x3F800000 always
            unsigned long long key =
                ((unsigned long long)(vb - 0x3F800000u) << 32) |
                (unsigned)(AA - 1 - a);
            pos_key[(size_t)b * AA + slot] = key;
        }
    }
    __syncthreads();
    int npos = s_cnt;
    if (tid == 0) { pos_cnt[b] = npos; atomicAdd(g_npos, npos); }
    int cap = npos * NEGRATIO;

    // inclusive scan over neg-pre mask, drop entries beyond cap
    int lane = tid & 63, wid = tid >> 6;
    int running = 0;
    for (int base = 0; base < AA; base += 1024) {
        int a = base + tid;
        int v = 0;
        if (a < AA && selmask[b * AA + a] == 1) v = 1;
        int c = v;
        #pragma unroll
        for (int d = 1; d < 64; d <<= 1) {
            int t = __shfl_up(c, d);
            if (lane >= d) c += t;
        }
        if (lane == 63) s_ws[wid] = c;
        __syncthreads();
        if (tid == 0) {
            int run = 0;
            for (int i = 0; i < 16; ++i) { int t = s_ws[i]; s_ws[i] = run; run += t; }
            s_tot = run;
        }
        __syncthreads();
        int cum = running + s_ws[wid] + c;   // inclusive cumsum
        if (v && cum > cap) selmask[b * AA + a] = 0;
        running += s_tot;
        __syncthreads();
    }

    // compact active rows (order irrelevant: consumed by commutative sums)
    for (int a = tid; a < AA; a += 1024) {
        if (selmask[b * AA + a] != 0) {
            int slot = atomicAdd(&s_act, 1);
            act_list[b * AA + slot] = a;
        }
    }
    __syncthreads();
    if (tid == 0) act_cnt[b] = s_act;
}

// ---------------------------------------------------------------------------
// K4: focal classification loss over the compacted active list.
// One 64-lane group per row; per-block LDS reduction -> ONE atomic per block.
// ---------------------------------------------------------------------------
__global__ __launch_bounds__(256) void k4_focal(
    const float* __restrict__ cls_p, const int* __restrict__ gtl,
    const int* __restrict__ gidx, const int* __restrict__ selmask,
    const int* __restrict__ act_list, const int* __restrict__ act_cnt,
    float* __restrict__ acc_cls) {
    int b = blockIdx.y;
    int n = act_cnt[b];
    int group = blockIdx.x * 4 + (threadIdx.x >> 6);
    int lane = threadIdx.x & 63;
    float fsum = 0.0f;
    for (int i = group; i < n; i += 32 * 4) {
        int a = act_list[b * AA + i];
        int r = b * AA + a;
        const float* x = cls_p + (size_t)r * CC;
        float e0 = x[lane];
        float e1 = (lane < CC - 64) ? x[64 + lane] : -3.0e38f;
        float m = fmaxf(e0, e1);
        for (int off = 32; off; off >>= 1) m = fmaxf(m, __shfl_xor(m, off));
        float s = expf(e0 - m) + ((lane < CC - 64) ? expf(e1 - m) : 0.0f);
        for (int off = 32; off; off >>= 1) s += __shfl_xor(s, off);
        if (lane == 0) {
            int sm = selmask[r];
            int lbl = (sm == 2) ? gtl[b * GG + gidx[r]] : 0;
            float pt = expf(x[lbl] - m) / s;
            pt = fminf(fmaxf(pt, 1e-6f), 1.0f - 1e-6f);
            float at = (lbl > 0) ? 0.25f : 0.75f;
            float om = 1.0f - pt;
            fsum += at * om * om * (-logf(pt));
        }
    }
    __shared__ float s4[4];
    if (lane == 0) s4[threadIdx.x >> 6] = fsum;
    __syncthreads();
    if (threadIdx.x == 0) {
        float t = s4[0] + s4[1] + s4[2] + s4[3];
        atomicAdd(acc_cls, t);
    }
}

// ---------------------------------------------------------------------------
// K5: box regression loss (smooth L1), positives from the compacted list.
// Per-block reduction -> ONE atomic per block.
// ---------------------------------------------------------------------------
__global__ __launch_bounds__(256) void k5_box(
    const float* __restrict__ box_p, const float* __restrict__ anchors,
    const float* __restrict__ gt_boxes, const int* __restrict__ gidx,
    const int* __restrict__ selmask, const int* __restrict__ act_list,
    const int* __restrict__ act_cnt, float* __restrict__ acc_box) {
#pragma clang fp contract(off)
    int b = blockIdx.y;
    int n = act_cnt[b];
    float lsum = 0.0f;
    for (int i = blockIdx.x * 256 + threadIdx.x; i < n; i += 8 * 256) {
        int a = act_list[b * AA + i];
        int r = b * AA + a;
        if (selmask[r] != 2) continue;
        int g = gidx[r];
        float m0 = gt_boxes[(b * GG + g) * 4 + 0] / 550.0f;
        float m1 = gt_boxes[(b * GG + g) * 4 + 1] / 550.0f;
        float m2 = gt_boxes[(b * GG + g) * 4 + 2] / 550.0f;
        float m3 = gt_boxes[(b * GG + g) * 4 + 3] / 550.0f;
        float4 an = ((const float4*)anchors)[a];
        float gcx = 0.5f * (m0 + m2), gcy = 0.5f * (m1 + m3);
        float gw = fmaxf(m2 - m0, 1e-6f), gh = fmaxf(m3 - m1, 1e-6f);
        float t0 = (gcx - an.x) / (an.z * 0.1f);
        float t1 = (gcy - an.y) / (an.w * 0.1f);
        float t2 = logf(gw / an.z) / 0.2f;
        float t3 = logf(gh / an.w) / 0.2f;
        const float* bp = box_p + (size_t)r * 4;
        float d;
        d = fabsf(bp[0] - t0); lsum += (d < 1.0f) ? 0.5f * d * d : d - 0.5f;
        d = fabsf(bp[1] - t1); lsum += (d < 1.0f) ? 0.5f * d * d : d - 0.5f;
        d = fabsf(bp[2] - t2); lsum += (d < 1.0f) ? 0.5f * d * d : d - 0.5f;
        d = fabsf(bp[3] - t3); lsum += (d < 1.0f) ? 0.5f * d * d : d - 0.5f;
    }
    for (int off = 32; off; off >>= 1) lsum += __shfl_xor(lsum, off);
    __shared__ float s4[4];
    if ((threadIdx.x & 63) == 0) s4[threadIdx.x >> 6] = lsum;
    __syncthreads();
    if (threadIdx.x == 0) {
        float t = s4[0] + s4[1] + s4[2] + s4[3];
        atomicAdd(acc_box, t);
    }
}

// ---------------------------------------------------------------------------
// K6: per-image top-min(npos,128) selection via MSB-first radix select on the
// unique 56-bit keys (exact: T = K-th largest key; select {key >= T}).
// Then counting-sort the selected set by matched gt index g (sum over the
// selection is commutative, so order is free) so K7 can cache the gt-mask
// row across consecutive k. Gathers coeffs + g per selected anchor.
// ---------------------------------------------------------------------------
__global__ __launch_bounds__(1024) void k6_select(
    const unsigned long long* __restrict__ pos_key, const int* __restrict__ pos_cnt,
    const int* __restrict__ gidx, const float* __restrict__ coeffs,
    int* __restrict__ sel_g, float* __restrict__ sel_coef, int* __restrict__ sel_cnt) {
    int b = blockIdx.x, tid = threadIdx.x;
    __shared__ unsigned long long s_keys[SELCAP];
    __shared__ int s_hist[256];
    __shared__ int s_sfx[256];
    __shared__ int s_wsum[4];
    __shared__ unsigned long long s_prefix;
    __shared__ int s_kk;
    __shared__ int s_nsel;
    __shared__ int s_sel_a[KPOS];
    __shared__ int s_sorted_a[KPOS];
    __shared__ int s_sorted_g[KPOS];
    __shared__ int s_gcnt[GG];

    int n = pos_cnt[b];
    int K = (n < KPOS) ? n : KPOS;
    const unsigned long long* keys;
    if (n <= SELCAP) {
        for (int i = tid; i < n; i += 1024) s_keys[i] = pos_key[(size_t)b * AA + i];
        keys = s_keys;
    } else {
        keys = pos_key + (size_t)b * AA;
    }
    if (tid == 0) { s_prefix = 0ULL; s_kk = KPOS; s_nsel = 0; }
    __syncthreads();

    if (n > KPOS) {
        for (int d = 6; d >= 0; --d) {
            unsigned long long pref = s_prefix;   // snapshot (post-barrier)
            int kk = s_kk;
            if (tid < 256) s_hist[tid] = 0;
            __syncthreads();
            unsigned long long mhi = ~((1ULL << (8 * (d + 1))) - 1ULL);
            for (int i = tid; i < n; i += 1024) {
                unsigned long long k = keys[i];
                if ((k & mhi) == pref)
                    atomicAdd(&s_hist[(int)((k >> (8 * d)) & 255)], 1);
            }
            __syncthreads();
            // suffix sums: s_sfx[v] = #candidates with digit >= v
            int x = 0;
            if (tid < 256) {
                x = s_hist[255 - tid];
                #pragma unroll
                for (int o = 1; o < 64; o <<= 1) {
                    int t = __shfl_up(x, o);
                    if ((tid & 63) >= o) x += t;
                }
                if ((tid & 63) == 63) s_wsum[tid >> 6] = x;
            }
            __syncthreads();
            if (tid == 0) {
                int run = 0;
                #pragma unroll
                for (int i = 0; i < 4; ++i) { int t = s_wsum[i]; s_wsum[i] = run; run += t; }
            }
            __syncthreads();
            if (tid < 256) s_sfx[255 - tid] = x + s_wsum[tid >> 6];
            __syncthreads();
            if (tid < 256) {
                int v = tid;
                int ge = s_sfx[v];
                int gt = (v == 255) ? 0 : s_sfx[v + 1];
                if (ge >= kk && gt < kk) {          // exactly one v
                    s_prefix = pref | ((unsigned long long)v << (8 * d));
                    s_kk = kk - gt;
                }
            }
            __syncthreads();
        }
    }

    unsigned long long T = (n > KPOS) ? s_prefix : 0ULL;
    for (int i = tid; i < n; i += 1024) {
        unsigned long long k = keys[i];
        if (k >= T) {
            int slot = atomicAdd(&s_nsel, 1);
            if (slot < KPOS)
                s_sel_a[slot] = AA - 1 - (int)(unsigned)(k & 0xffffffffu);
        }
    }
    __syncthreads();

    // counting sort by g
    if (tid < GG) s_gcnt[tid] = 0;
    __syncthreads();
    int mya = -1, myg = -1;
    if (tid < K) {
        mya = s_sel_a[tid];
        myg = gidx[b * AA + mya];
        atomicAdd(&s_gcnt[myg], 1);
    }
    __syncthreads();
    if (tid == 0) {
        int run = 0;
        for (int g = 0; g < GG; ++g) { int c = s_gcnt[g]; s_gcnt[g] = run; run += c; }
    }
    __syncthreads();
    if (tid < K) {
        int pos = atomicAdd(&s_gcnt[myg], 1);
        s_sorted_a[pos] = mya;
        s_sorted_g[pos] = myg;
    }
    __syncthreads();

    if (tid == 0) sel_cnt[b] = K;
    for (int t = tid; t < K * PP; t += 1024) {
        int k = t >> 5, p = t & 31;
        int a = s_sorted_a[k];
        sel_coef[(b * KPOS + k) * PP + p] = coeffs[((size_t)(b * AA + a)) * PP + p];
    }
    for (int t = tid; t < K; t += 1024)
        sel_g[b * KPOS + t] = s_sorted_g[t];
}

// ---------------------------------------------------------------------------
// K7: mask loss — logits = coeffs_sel(<=128 x 32) x protos(32 x 19044) + BCE.
// protos in registers; coeffs via float4 ds_read; 2 k's per iteration with
// 4 independent FMA chains (hides v_fma latency); selection is g-sorted so
// the gt-mask pixel is reloaded only on group change (<=32 loads/pixel);
// fast __expf/__logf BCE (error averages out, threshold is loose).
// ---------------------------------------------------------------------------
__global__ __launch_bounds__(128) void k7_mask(
    const float* __restrict__ protos, const float* __restrict__ gtm,
    const float* __restrict__ sel_coef, const int* __restrict__ sel_g,
    const int* __restrict__ sel_cnt, float* __restrict__ acc_mask) {
    int b = blockIdx.y;
    int pix = blockIdx.x * 128 + threadIdx.x;
    __shared__ float s_c[KPOS * PP];
    __shared__ int s_g[KPOS];
    __shared__ float s_red[2];
    int nk = sel_cnt[b];
    for (int t = threadIdx.x; t < nk * PP; t += 128) s_c[t] = sel_coef[b * KPOS * PP + t];
    for (int t = threadIdx.x; t < nk; t += 128) s_g[t] = sel_g[b * KPOS + t];
    __syncthreads();
    bool valid = pix < PHW;
    int pc = valid ? pix : 0;
    float pr[PP];
    #pragma unroll
    for (int p = 0; p < PP; ++p)
        pr[p] = protos[((size_t)(b * PP + p)) * PHW + pc];
    const float* gtm_b = gtm + (size_t)b * GG * PHW + pc;

    float acc = 0.0f;
    int gprev = -1;
    float t = 0.0f;
    int k = 0;
    for (; k + 2 <= nk; k += 2) {
        int g0 = s_g[k], g1 = s_g[k + 1];
        const float4* c0 = (const float4*)&s_c[k * PP];
        const float4* c1 = (const float4*)&s_c[(k + 1) * PP];
        float l0a = 0.0f, l0b = 0.0f, l1a = 0.0f, l1b = 0.0f;
        #pragma unroll
        for (int q = 0; q < 8; q += 2) {
            float4 u0 = c0[q], u1 = c0[q + 1];
            float4 v0 = c1[q], v1 = c1[q + 1];
            l0a += u0.x * pr[4 * q + 0]; l0b += u1.x * pr[4 * q + 4];
            l1a += v0.x * pr[4 * q + 0]; l1b += v1.x * pr[4 * q + 4];
            l0a += u0.y * pr[4 * q + 1]; l0b += u1.y * pr[4 * q + 5];
            l1a += v0.y * pr[4 * q + 1]; l1b += v1.y * pr[4 * q + 5];
            l0a += u0.z * pr[4 * q + 2]; l0b += u1.z * pr[4 * q + 6];
            l1a += v0.z * pr[4 * q + 2]; l1b += v1.z * pr[4 * q + 6];
            l0a += u0.w * pr[4 * q + 3]; l0b += u1.w * pr[4 * q + 7];
            l1a += v0.w * pr[4 * q + 3]; l1b += v1.w * pr[4 * q + 7];
        }
        float l0 = l0a + l0b, l1 = l1a + l1b;
        if (g0 != gprev) { t = gtm_b[(size_t)g0 * PHW]; gprev = g0; }
        acc += fmaxf(l0, 0.0f) - l0 * t + __logf(1.0f + __expf(-fabsf(l0)));
        if (g1 != gprev) { t = gtm_b[(size_t)g1 * PHW]; gprev = g1; }
        acc += fmaxf(l1, 0.0f) - l1 * t + __logf(1.0f + __expf(-fabsf(l1)));
    }
    for (; k < nk; ++k) {
        int g0 = s_g[k];
        const float4* c0 = (const float4*)&s_c[k * PP];
        float l0a = 0.0f, l0b = 0.0f;
        #pragma unroll
        for (int q = 0; q < 8; q += 2) {
            float4 u0 = c0[q], u1 = c0[q + 1];
            l0a += u0.x * pr[4 * q + 0]; l0b += u1.x * pr[4 * q + 4];
            l0a += u0.y * pr[4 * q + 1]; l0b += u1.y * pr[4 * q + 5];
            l0a += u0.z * pr[4 * q + 2]; l0b += u1.z * pr[4 * q + 6];
            l0a += u0.w * pr[4 * q + 3]; l0b += u1.w * pr[4 * q + 7];
        }
        float l0 = l0a + l0b;
        if (g0 != gprev) { t = gtm_b[(size_t)g0 * PHW]; gprev = g0; }
        acc += fmaxf(l0, 0.0f) - l0 * t + __logf(1.0f + __expf(-fabsf(l0)));
    }
    if (!valid) acc = 0.0f;
    for (int off = 32; off; off >>= 1) acc += __shfl_xor(acc, off);
    if ((threadIdx.x & 63) == 0) s_red[threadIdx.x >> 6] = acc;
    __syncthreads();
    if (threadIdx.x == 0)
        atomicAdd(acc_mask, s_red[0] + s_red[1]);
}

// ---------------------------------------------------------------------------
// K8: finalize.
// ---------------------------------------------------------------------------
__global__ void k8_final(const float* __restrict__ acc, const int* __restrict__ npos,
                         float* __restrict__ out) {
    float denom = fmaxf((float)(*npos), 1.0f);
    out[0] = (1.0f * acc[0] + 1.5f * acc[1] + 6.125f * (acc[2] / (float)PHW)) / denom;
}

// ---------------------------------------------------------------------------
extern "C" void kernel_launch(void* const* d_in, const int* in_sizes, int n_in,
                              void* d_out, int out_size, void* d_ws, size_t ws_size,
                              hipStream_t stream) {
    (void)in_sizes; (void)n_in; (void)out_size; (void)ws_size;
    const float* class_preds = (const float*)d_in[0];
    const float* box_preds   = (const float*)d_in[1];
    const float* mask_coeffs = (const float*)d_in[2];
    const float* prototypes  = (const float*)d_in[3];
    const float* anchors     = (const float*)d_in[4];
    const float* gt_boxes    = (const float*)d_in[5];
    const int*   gt_labels   = (const int*)d_in[6];
    const float* gt_masks    = (const float*)d_in[7];
    float* out = (float*)d_out;

    size_t off = 0;
    char* w = (char*)d_ws;
    auto take = [&](size_t bytes) -> char* {
        char* p = w + off;
        off += (bytes + 255) & ~(size_t)255;
        return p;
    };
    float* acc      = (float*)take(32);                       // [cls, box, mask, npos(int)]
    float* best_iou = (float*)take((size_t)BB * AA * 4);
    int*   best_g   = (int*)  take((size_t)BB * AA * 4);
    int*   gidx     = (int*)  take((size_t)BB * AA * 4);
    int*   selmask  = (int*)  take((size_t)BB * AA * 4);
    int*   banchor  = (int*)  take((size_t)BB * GG * 4);
    int*   pos_cnt  = (int*)  take((size_t)BB * 4);
    unsigned long long* pos_key = (unsigned long long*)take((size_t)BB * AA * 8);
    int*   sel_g    = (int*)  take((size_t)BB * KPOS * 4);
    int*   sel_cnt  = (int*)  take((size_t)BB * 4);
    float* sel_coef = (float*)take((size_t)BB * KPOS * PP * 4);
    int*   act_list = (int*)  take((size_t)BB * AA * 4);
    int*   act_cnt  = (int*)  take((size_t)BB * 4);

    hipMemsetAsync(acc, 0, 32, stream);

    k1_best_per_anchor<<<dim3((AA + 255) / 256, BB), 256, 0, stream>>>(
        anchors, gt_boxes, best_iou, best_g);
    k2_best_anchor_per_gt<<<dim3(GG, BB), 256, 0, stream>>>(
        anchors, gt_boxes, banchor);
    k3_match_scan<<<BB, 1024, 0, stream>>>(
        best_iou, best_g, banchor, gidx, selmask, pos_key, pos_cnt, (int*)(acc + 3),
        act_list, act_cnt);
    k4_focal<<<dim3(32, BB), 256, 0, stream>>>(
        class_preds, gt_labels, gidx, selmask, act_list, act_cnt, acc + 0);
    k5_box<<<dim3(8, BB), 256, 0, stream>>>(
        box_preds, anchors, gt_boxes, gidx, selmask, act_list, act_cnt, acc + 1);
    k6_select<<<BB, 1024, 0, stream>>>(
        pos_key, pos_cnt, gidx, mask_coeffs, sel_g, sel_coef, sel_cnt);
    k7_mask<<<dim3((PHW + 127) / 128, BB), 128, 0, stream>>>(
        prototypes, gt_masks, sel_coef, sel_g, sel_cnt, acc + 2);
    k8_final<<<1, 1, 0, stream>>>(acc, (int*)(acc + 3), out);
}

// Round 5
// 189.388 us; speedup vs baseline: 3.5221x; 1.0141x over previous
//
#include <hip/hip_runtime.h>
#include <math.h>

#define BB 8
#define AA 19248
#define GG 32
#define CC 81
#define PP 32
#define PHW 19044   /* 138*138 */
#define KPOS 128
#define NEGRATIO 3
#define SELCAP 7680
#define NWCH 304    /* 19 outer iters x 16 waves of 64 anchors */
#define KSPLIT 2
#define KBLK (KPOS / KSPLIT)

// ---------------------------------------------------------------------------
// IoU helper — contraction off so K1 and K2 produce bitwise-identical values
// and FMA fusion can't flip threshold/argmax decisions vs the XLA reference.
// ---------------------------------------------------------------------------
__device__ __forceinline__ float iou_one(float ax1, float ay1, float ax2, float ay2,
                                         float areaA,
                                         float gx1, float gy1, float gx2, float gy2) {
#pragma clang fp contract(off)
    float ix1 = fmaxf(ax1, gx1), iy1 = fmaxf(ay1, gy1);
    float ix2 = fminf(ax2, gx2), iy2 = fminf(ay2, gy2);
    float iw = fmaxf(ix2 - ix1, 0.0f), ih = fmaxf(iy2 - iy1, 0.0f);
    float inter = iw * ih;
    float areaB = (gx2 - gx1) * (gy2 - gy1);
    float u = areaA + areaB - inter;
    u = fmaxf(u, 1e-6f);
    return inter / u;
}

// ---------------------------------------------------------------------------
// K1: per (b,a) best IoU + first-max argmax over the 32 GT boxes.
// ---------------------------------------------------------------------------
__global__ void k1_best_per_anchor(const float* __restrict__ anchors,
                                   const float* __restrict__ gt_boxes,
                                   float* __restrict__ best_iou,
                                   int* __restrict__ best_g) {
#pragma clang fp contract(off)
    int b = blockIdx.y;
    int a = blockIdx.x * 256 + threadIdx.x;
    __shared__ float sg[GG][4];
    for (int t = threadIdx.x; t < GG * 4; t += 256)
        sg[t >> 2][t & 3] = gt_boxes[b * GG * 4 + t] / 550.0f;
    __syncthreads();
    if (a >= AA) return;
    float4 an = ((const float4*)anchors)[a];
    float ax1 = an.x - an.z * 0.5f, ay1 = an.y - an.w * 0.5f;
    float ax2 = an.x + an.z * 0.5f, ay2 = an.y + an.w * 0.5f;
    float areaA = (ax2 - ax1) * (ay2 - ay1);
    float best = -1.0f; int bi = 0;
    for (int g = 0; g < GG; ++g) {
        float v = iou_one(ax1, ay1, ax2, ay2, areaA, sg[g][0], sg[g][1], sg[g][2], sg[g][3]);
        if (v > best) { best = v; bi = g; }  // strict > keeps FIRST max (jnp.argmax)
    }
    best_iou[b * AA + a] = best;
    best_g[b * AA + a] = bi;
}

// ---------------------------------------------------------------------------
// K2: per (b,g) argmax over all anchors (first occurrence on ties -> packed
// key with inverted index, take max).
// ---------------------------------------------------------------------------
__global__ void k2_best_anchor_per_gt(const float* __restrict__ anchors,
                                      const float* __restrict__ gt_boxes,
                                      int* __restrict__ best_anchor) {
#pragma clang fp contract(off)
    int b = blockIdx.y, g = blockIdx.x;
    float gx1 = gt_boxes[(b * GG + g) * 4 + 0] / 550.0f;
    float gy1 = gt_boxes[(b * GG + g) * 4 + 1] / 550.0f;
    float gx2 = gt_boxes[(b * GG + g) * 4 + 2] / 550.0f;
    float gy2 = gt_boxes[(b * GG + g) * 4 + 3] / 550.0f;
    unsigned long long lk = 0ULL;
    const float4* a4 = (const float4*)anchors;
    for (int a = threadIdx.x; a < AA; a += 256) {
        float4 an = a4[a];
        float ax1 = an.x - an.z * 0.5f, ay1 = an.y - an.w * 0.5f;
        float ax2 = an.x + an.z * 0.5f, ay2 = an.y + an.w * 0.5f;
        float areaA = (ax2 - ax1) * (ay2 - ay1);
        float v = iou_one(ax1, ay1, ax2, ay2, areaA, gx1, gy1, gx2, gy2);
        unsigned long long key =
            ((unsigned long long)__float_as_uint(v) << 32) | (unsigned)(AA - 1 - a);
        if (key > lk) lk = key;
    }
    for (int off = 32; off; off >>= 1) {
        unsigned long long o = __shfl_xor(lk, off);
        if (o > lk) lk = o;
    }
    __shared__ unsigned long long sk[4];
    if ((threadIdx.x & 63) == 0) sk[threadIdx.x >> 6] = lk;
    __syncthreads();
    if (threadIdx.x == 0) {
        unsigned long long m = sk[0];
        for (int i = 1; i < 4; ++i) if (sk[i] > m) m = sk[i];
        best_anchor[b * GG + g] = AA - 1 - (int)(unsigned)(m & 0xffffffffu);
    }
}

// ---------------------------------------------------------------------------
// K3: per image — scatter overrides (ascending g loop -> last wins, matching
// XLA scatter), pos compaction + keys, hard-negative cap via ballot-based
// scan (2 passes, ~6 barriers instead of ~76), active-row compaction.
// selmask: 0 = unused, 1 = neg, 2 = pos.
// ---------------------------------------------------------------------------
__global__ __launch_bounds__(1024) void k3_match_scan(
    const float* __restrict__ best_iou, const int* __restrict__ best_g_in,
    const int* __restrict__ best_anchor,
    int* __restrict__ gidx_out, int* __restrict__ selmask,
    unsigned long long* __restrict__ pos_key,
    int* __restrict__ pos_cnt, int* __restrict__ g_npos,
    int* __restrict__ act_list, int* __restrict__ act_cnt) {
#pragma clang fp contract(off)
    int b = blockIdx.x;
    int tid = threadIdx.x;
    int lane = tid & 63, wid = tid >> 6;
    __shared__ int sba[GG];
    __shared__ unsigned long long s_pmask[NWCH];
    __shared__ unsigned long long s_nmask[NWCH];
    __shared__ int s_woff[NWCH];
    __shared__ int s_wred[5];
    __shared__ int s_cnt, s_act;
    if (tid < GG) sba[tid] = best_anchor[b * GG + tid];
    if (tid == 0) { s_cnt = 0; s_act = 0; }
    __syncthreads();

    // pass 1: matching decisions + pos keys + per-wave-chunk ballots
    for (int base = 0; base < AA; base += 1024) {
        int a = base + tid;
        bool p = false, npre = false;
        if (a < AA) {
            float biou = best_iou[b * AA + a];
            int gi = best_g_in[b * AA + a];
            p = (biou >= 0.5f);
            for (int g = 0; g < GG; ++g)
                if (sba[g] == a) { p = true; gi = g; }   // ascending -> last wins
            npre = (biou < 0.4f) && !p;
            gidx_out[b * AA + a] = gi;
            selmask[b * AA + a] = p ? 2 : (npre ? 1 : 0);
            if (p) {
                int slot = atomicAdd(&s_cnt, 1);
                unsigned vb = __float_as_uint(biou + 1.0f);   // >= 0x3F800000
                unsigned long long key =
                    ((unsigned long long)(vb - 0x3F800000u) << 32) |
                    (unsigned)(AA - 1 - a);
                pos_key[(size_t)b * AA + slot] = key;
            }
        }
        unsigned long long pm = __ballot(p);
        unsigned long long nm = __ballot(npre);
        if (lane == 0) {
            int w = (base >> 6) + wid;
            s_pmask[w] = pm;
            s_nmask[w] = nm;
        }
    }
    __syncthreads();
    int npos = s_cnt;
    if (tid == 0) { pos_cnt[b] = npos; atomicAdd(g_npos, npos); }
    int cap = npos * NEGRATIO;

    // scan 304 chunk counts with 5 waves
    int c = (tid < NWCH) ? __popcll(s_nmask[tid]) : 0;
    int inc = c;
    if (wid < 5) {
        #pragma unroll
        for (int d = 1; d < 64; d <<= 1) {
            int t = __shfl_up(inc, d);
            if (lane >= d) inc += t;
        }
        if (lane == 63) s_wred[wid] = inc;
    }
    __syncthreads();
    if (tid == 0) {
        int run = 0;
        #pragma unroll
        for (int i = 0; i < 5; ++i) { int t = s_wred[i]; s_wred[i] = run; run += t; }
    }
    __syncthreads();
    if (tid < NWCH) s_woff[tid] = inc - c + s_wred[wid];   // exclusive prefix
    __syncthreads();

    // pass 2: drop negs beyond cap, compact active rows (order-free)
    for (int base = 0; base < AA; base += 1024) {
        int a = base + tid;
        int w = (base >> 6) + wid;
        unsigned long long nm = s_nmask[w], pm = s_pmask[w];
        bool npre = (nm >> lane) & 1ULL;
        bool pos  = (pm >> lane) & 1ULL;
        int rank = __popcll(nm & ((1ULL << lane) - 1ULL));
        bool kept = npre && (s_woff[w] + rank + 1 <= cap);
        if (a < AA) {
            if (npre && !kept) selmask[b * AA + a] = 0;
            if (pos || kept) {
                int slot = atomicAdd(&s_act, 1);
                act_list[b * AA + slot] = a;
            }
        }
    }
    __syncthreads();
    if (tid == 0) act_cnt[b] = s_act;
}

// ---------------------------------------------------------------------------
// K45: focal classification + box loss fused over the compacted active list.
// One 64-lane group per row; lane 0 adds the box term for positive rows.
// Per-block LDS reduction -> one atomic per block per accumulator.
// ---------------------------------------------------------------------------
__global__ __launch_bounds__(256) void k45_cls_box(
    const float* __restrict__ cls_p, const int* __restrict__ gtl,
    const int* __restrict__ gidx, const int* __restrict__ selmask,
    const int* __restrict__ act_list, const int* __restrict__ act_cnt,
    const float* __restrict__ box_p, const float* __restrict__ anchors,
    const float* __restrict__ gt_boxes, float* __restrict__ acc) {
    int b = blockIdx.y;
    int n = act_cnt[b];
    int group = blockIdx.x * 4 + (threadIdx.x >> 6);
    int lane = threadIdx.x & 63;
    float fsum = 0.0f, bsum = 0.0f;
    for (int i = group; i < n; i += 32 * 4) {
        int a = act_list[b * AA + i];
        int r = b * AA + a;
        const float* x = cls_p + (size_t)r * CC;
        float e0 = x[lane];
        float e1 = (lane < CC - 64) ? x[64 + lane] : -3.0e38f;
        float m = fmaxf(e0, e1);
        for (int off = 32; off; off >>= 1) m = fmaxf(m, __shfl_xor(m, off));
        float s = expf(e0 - m) + ((lane < CC - 64) ? expf(e1 - m) : 0.0f);
        for (int off = 32; off; off >>= 1) s += __shfl_xor(s, off);
        if (lane == 0) {
            int sm = selmask[r];
            int g = gidx[r];
            int lbl = (sm == 2) ? gtl[b * GG + g] : 0;
            float pt = expf(x[lbl] - m) / s;
            pt = fminf(fmaxf(pt, 1e-6f), 1.0f - 1e-6f);
            float at = (lbl > 0) ? 0.25f : 0.75f;
            float om = 1.0f - pt;
            fsum += at * om * om * (-logf(pt));
            if (sm == 2) {
                float m0 = gt_boxes[(b * GG + g) * 4 + 0] / 550.0f;
                float m1 = gt_boxes[(b * GG + g) * 4 + 1] / 550.0f;
                float m2 = gt_boxes[(b * GG + g) * 4 + 2] / 550.0f;
                float m3 = gt_boxes[(b * GG + g) * 4 + 3] / 550.0f;
                float4 an = ((const float4*)anchors)[a];
                float gcx = 0.5f * (m0 + m2), gcy = 0.5f * (m1 + m3);
                float gw = fmaxf(m2 - m0, 1e-6f), gh = fmaxf(m3 - m1, 1e-6f);
                float t0 = (gcx - an.x) / (an.z * 0.1f);
                float t1 = (gcy - an.y) / (an.w * 0.1f);
                float t2 = logf(gw / an.z) / 0.2f;
                float t3 = logf(gh / an.w) / 0.2f;
                const float* bp = box_p + (size_t)r * 4;
                float d;
                d = fabsf(bp[0] - t0); bsum += (d < 1.0f) ? 0.5f * d * d : d - 0.5f;
                d = fabsf(bp[1] - t1); bsum += (d < 1.0f) ? 0.5f * d * d : d - 0.5f;
                d = fabsf(bp[2] - t2); bsum += (d < 1.0f) ? 0.5f * d * d : d - 0.5f;
                d = fabsf(bp[3] - t3); bsum += (d < 1.0f) ? 0.5f * d * d : d - 0.5f;
            }
        }
    }
    __shared__ float s4f[4], s4b[4];
    if (lane == 0) { s4f[threadIdx.x >> 6] = fsum; s4b[threadIdx.x >> 6] = bsum; }
    __syncthreads();
    if (threadIdx.x == 0) {
        atomicAdd(acc + 0, s4f[0] + s4f[1] + s4f[2] + s4f[3]);
        atomicAdd(acc + 1, s4b[0] + s4b[1] + s4b[2] + s4b[3]);
    }
}

// ---------------------------------------------------------------------------
// K6: per-image top-min(npos,128) via MSB-first radix select on unique 56-bit
// keys, then counting-sort selection by matched gt index g (order within the
// selection is free — commutative sum, all weights 1). Gathers coeffs + g.
// ---------------------------------------------------------------------------
__global__ __launch_bounds__(1024) void k6_select(
    const unsigned long long* __restrict__ pos_key, const int* __restrict__ pos_cnt,
    const int* __restrict__ gidx, const float* __restrict__ coeffs,
    int* __restrict__ sel_g, float* __restrict__ sel_coef, int* __restrict__ sel_cnt) {
    int b = blockIdx.x, tid = threadIdx.x;
    __shared__ unsigned long long s_keys[SELCAP];
    __shared__ int s_hist[256];
    __shared__ int s_sfx[256];
    __shared__ int s_wsum[4];
    __shared__ unsigned long long s_prefix;
    __shared__ int s_kk;
    __shared__ int s_nsel;
    __shared__ int s_sel_a[KPOS];
    __shared__ int s_sorted_a[KPOS];
    __shared__ int s_sorted_g[KPOS];
    __shared__ int s_gcnt[GG];

    int n = pos_cnt[b];
    int K = (n < KPOS) ? n : KPOS;
    const unsigned long long* keys;
    if (n <= SELCAP) {
        for (int i = tid; i < n; i += 1024) s_keys[i] = pos_key[(size_t)b * AA + i];
        keys = s_keys;
    } else {
        keys = pos_key + (size_t)b * AA;
    }
    if (tid == 0) { s_prefix = 0ULL; s_kk = KPOS; s_nsel = 0; }
    __syncthreads();

    if (n > KPOS) {
        for (int d = 6; d >= 0; --d) {
            unsigned long long pref = s_prefix;   // snapshot (post-barrier)
            int kk = s_kk;
            if (tid < 256) s_hist[tid] = 0;
            __syncthreads();
            unsigned long long mhi = ~((1ULL << (8 * (d + 1))) - 1ULL);
            for (int i = tid; i < n; i += 1024) {
                unsigned long long k = keys[i];
                if ((k & mhi) == pref)
                    atomicAdd(&s_hist[(int)((k >> (8 * d)) & 255)], 1);
            }
            __syncthreads();
            int x = 0;
            if (tid < 256) {
                x = s_hist[255 - tid];
                #pragma unroll
                for (int o = 1; o < 64; o <<= 1) {
                    int t = __shfl_up(x, o);
                    if ((tid & 63) >= o) x += t;
                }
                if ((tid & 63) == 63) s_wsum[tid >> 6] = x;
            }
            __syncthreads();
            if (tid == 0) {
                int run = 0;
                #pragma unroll
                for (int i = 0; i < 4; ++i) { int t = s_wsum[i]; s_wsum[i] = run; run += t; }
            }
            __syncthreads();
            if (tid < 256) s_sfx[255 - tid] = x + s_wsum[tid >> 6];
            __syncthreads();
            if (tid < 256) {
                int v = tid;
                int ge = s_sfx[v];
                int gt = (v == 255) ? 0 : s_sfx[v + 1];
                if (ge >= kk && gt < kk) {
                    s_prefix = pref | ((unsigned long long)v << (8 * d));
                    s_kk = kk - gt;
                }
            }
            __syncthreads();
        }
    }

    unsigned long long T = (n > KPOS) ? s_prefix : 0ULL;
    for (int i = tid; i < n; i += 1024) {
        unsigned long long k = keys[i];
        if (k >= T) {
            int slot = atomicAdd(&s_nsel, 1);
            if (slot < KPOS)
                s_sel_a[slot] = AA - 1 - (int)(unsigned)(k & 0xffffffffu);
        }
    }
    __syncthreads();

    if (tid < GG) s_gcnt[tid] = 0;
    __syncthreads();
    int mya = -1, myg = -1;
    if (tid < K) {
        mya = s_sel_a[tid];
        myg = gidx[b * AA + mya];
        atomicAdd(&s_gcnt[myg], 1);
    }
    __syncthreads();
    if (tid == 0) {
        int run = 0;
        for (int g = 0; g < GG; ++g) { int c = s_gcnt[g]; s_gcnt[g] = run; run += c; }
    }
    __syncthreads();
    if (tid < K) {
        int pos = atomicAdd(&s_gcnt[myg], 1);
        s_sorted_a[pos] = mya;
        s_sorted_g[pos] = myg;
    }
    __syncthreads();

    if (tid == 0) sel_cnt[b] = K;
    for (int t = tid; t < K * PP; t += 1024) {
        int k = t >> 5, p = t & 31;
        int a = s_sorted_a[k];
        sel_coef[(b * KPOS + k) * PP + p] = coeffs[((size_t)(b * AA + a)) * PP + p];
    }
    for (int t = tid; t < K; t += 1024)
        sel_g[b * KPOS + t] = s_sorted_g[t];
}

// ---------------------------------------------------------------------------
// K7: mask loss. 4 pixels/thread (float4) so the wave-uniform LDS coeff reads
// are amortized 4x (the round-4 bottleneck: LDS return-path throughput).
// K split across KSPLIT block groups (output rows independent). Protos in
// 32 float4 registers; 4 independent float4 FMA chains; g-sorted gt reload.
// ---------------------------------------------------------------------------
__device__ __forceinline__ float4 fma4(float s, float4 p, float4 a) {
    a.x += s * p.x; a.y += s * p.y; a.z += s * p.z; a.w += s * p.w;
    return a;
}
__device__ __forceinline__ float4 add4(float4 a, float4 b) {
    a.x += b.x; a.y += b.y; a.z += b.z; a.w += b.w;
    return a;
}
__device__ __forceinline__ float4 bce4(float4 l, float4 t, float4 a) {
    a.x += fmaxf(l.x, 0.f) - l.x * t.x + __logf(1.f + __expf(-fabsf(l.x)));
    a.y += fmaxf(l.y, 0.f) - l.y * t.y + __logf(1.f + __expf(-fabsf(l.y)));
    a.z += fmaxf(l.z, 0.f) - l.z * t.z + __logf(1.f + __expf(-fabsf(l.z)));
    a.w += fmaxf(l.w, 0.f) - l.w * t.w + __logf(1.f + __expf(-fabsf(l.w)));
    return a;
}

__global__ __launch_bounds__(128) void k7_mask(
    const float* __restrict__ protos, const float* __restrict__ gtm,
    const float* __restrict__ sel_coef, const int* __restrict__ sel_g,
    const int* __restrict__ sel_cnt, float* __restrict__ acc_mask) {
    int b = blockIdx.z;
    int nk = sel_cnt[b];
    int k0 = blockIdx.y * KBLK;
    if (k0 >= nk) return;                       // uniform early-exit, pre-barrier
    int nkb = min(nk, k0 + KBLK) - k0;
    int pix0 = (blockIdx.x * 128 + threadIdx.x) * 4;

    __shared__ float s_c[KBLK * PP];
    __shared__ int s_g[KBLK];
    __shared__ float s_red[2];
    for (int t = threadIdx.x; t < nkb * PP; t += 128)
        s_c[t] = sel_coef[(b * KPOS + k0) * PP + t];
    for (int t = threadIdx.x; t < nkb; t += 128)
        s_g[t] = sel_g[b * KPOS + k0 + t];
    __syncthreads();

    bool valid = pix0 < PHW;
    int pc = valid ? pix0 : 0;
    float4 pr[PP];
    #pragma unroll
    for (int p = 0; p < PP; ++p)
        pr[p] = *(const float4*)&protos[((size_t)(b * PP + p)) * PHW + pc];
    const float* gtm_b = gtm + (size_t)b * GG * PHW + pc;

    float4 acc4 = make_float4(0.f, 0.f, 0.f, 0.f);
    float4 t4 = make_float4(0.f, 0.f, 0.f, 0.f);
    int gprev = -1;
    int k = 0;
    for (; k + 2 <= nkb; k += 2) {
        const float4* c0 = (const float4*)&s_c[k * PP];
        const float4* c1 = c0 + 8;
        float4 a0 = make_float4(0.f, 0.f, 0.f, 0.f), b0 = a0, a1 = a0, b1 = a0;
        #pragma unroll
        for (int q = 0; q < 8; ++q) {
            float4 u = c0[q], v = c1[q];
            float4 p0 = pr[4 * q + 0], p1 = pr[4 * q + 1];
            float4 p2 = pr[4 * q + 2], p3 = pr[4 * q + 3];
            a0 = fma4(u.x, p0, a0); b0 = fma4(u.y, p1, b0);
            a0 = fma4(u.z, p2, a0); b0 = fma4(u.w, p3, b0);
            a1 = fma4(v.x, p0, a1); b1 = fma4(v.y, p1, b1);
            a1 = fma4(v.z, p2, a1); b1 = fma4(v.w, p3, b1);
        }
        float4 l0 = add4(a0, b0), l1 = add4(a1, b1);
        int g0 = s_g[k], g1 = s_g[k + 1];
        if (g0 != gprev) { t4 = *(const float4*)&gtm_b[(size_t)g0 * PHW]; gprev = g0; }
        acc4 = bce4(l0, t4, acc4);
        if (g1 != gprev) { t4 = *(const float4*)&gtm_b[(size_t)g1 * PHW]; gprev = g1; }
        acc4 = bce4(l1, t4, acc4);
    }
    for (; k < nkb; ++k) {
        const float4* c0 = (const float4*)&s_c[k * PP];
        float4 a0 = make_float4(0.f, 0.f, 0.f, 0.f), b0 = a0;
        #pragma unroll
        for (int q = 0; q < 8; ++q) {
            float4 u = c0[q];
            a0 = fma4(u.x, pr[4 * q + 0], a0); b0 = fma4(u.y, pr[4 * q + 1], b0);
            a0 = fma4(u.z, pr[4 * q + 2], a0); b0 = fma4(u.w, pr[4 * q + 3], b0);
        }
        float4 l0 = add4(a0, b0);
        int g0 = s_g[k];
        if (g0 != gprev) { t4 = *(const float4*)&gtm_b[(size_t)g0 * PHW]; gprev = g0; }
        acc4 = bce4(l0, t4, acc4);
    }

    float acc = valid ? (acc4.x + acc4.y + acc4.z + acc4.w) : 0.0f;
    for (int off = 32; off; off >>= 1) acc += __shfl_xor(acc, off);
    if ((threadIdx.x & 63) == 0) s_red[threadIdx.x >> 6] = acc;
    __syncthreads();
    if (threadIdx.x == 0)
        atomicAdd(acc_mask, s_red[0] + s_red[1]);
}

// ---------------------------------------------------------------------------
// K8: finalize.
// ---------------------------------------------------------------------------
__global__ void k8_final(const float* __restrict__ acc, const int* __restrict__ npos,
                         float* __restrict__ out) {
    float denom = fmaxf((float)(*npos), 1.0f);
    out[0] = (1.0f * acc[0] + 1.5f * acc[1] + 6.125f * (acc[2] / (float)PHW)) / denom;
}

// ---------------------------------------------------------------------------
extern "C" void kernel_launch(void* const* d_in, const int* in_sizes, int n_in,
                              void* d_out, int out_size, void* d_ws, size_t ws_size,
                              hipStream_t stream) {
    (void)in_sizes; (void)n_in; (void)out_size; (void)ws_size;
    const float* class_preds = (const float*)d_in[0];
    const float* box_preds   = (const float*)d_in[1];
    const float* mask_coeffs = (const float*)d_in[2];
    const float* prototypes  = (const float*)d_in[3];
    const float* anchors     = (const float*)d_in[4];
    const float* gt_boxes    = (const float*)d_in[5];
    const int*   gt_labels   = (const int*)d_in[6];
    const float* gt_masks    = (const float*)d_in[7];
    float* out = (float*)d_out;

    size_t off = 0;
    char* w = (char*)d_ws;
    auto take = [&](size_t bytes) -> char* {
        char* p = w + off;
        off += (bytes + 255) & ~(size_t)255;
        return p;
    };
    float* acc      = (float*)take(32);                       // [cls, box, mask, npos(int)]
    float* best_iou = (float*)take((size_t)BB * AA * 4);
    int*   best_g   = (int*)  take((size_t)BB * AA * 4);
    int*   gidx     = (int*)  take((size_t)BB * AA * 4);
    int*   selmask  = (int*)  take((size_t)BB * AA * 4);
    int*   banchor  = (int*)  take((size_t)BB * GG * 4);
    int*   pos_cnt  = (int*)  take((size_t)BB * 4);
    unsigned long long* pos_key = (unsigned long long*)take((size_t)BB * AA * 8);
    int*   sel_g    = (int*)  take((size_t)BB * KPOS * 4);
    int*   sel_cnt  = (int*)  take((size_t)BB * 4);
    float* sel_coef = (float*)take((size_t)BB * KPOS * PP * 4);
    int*   act_list = (int*)  take((size_t)BB * AA * 4);
    int*   act_cnt  = (int*)  take((size_t)BB * 4);

    hipMemsetAsync(acc, 0, 32, stream);

    k1_best_per_anchor<<<dim3((AA + 255) / 256, BB), 256, 0, stream>>>(
        anchors, gt_boxes, best_iou, best_g);
    k2_best_anchor_per_gt<<<dim3(GG, BB), 256, 0, stream>>>(
        anchors, gt_boxes, banchor);
    k3_match_scan<<<BB, 1024, 0, stream>>>(
        best_iou, best_g, banchor, gidx, selmask, pos_key, pos_cnt, (int*)(acc + 3),
        act_list, act_cnt);
    k45_cls_box<<<dim3(32, BB), 256, 0, stream>>>(
        class_preds, gt_labels, gidx, selmask, act_list, act_cnt,
        box_preds, anchors, gt_boxes, acc);
    k6_select<<<BB, 1024, 0, stream>>>(
        pos_key, pos_cnt, gidx, mask_coeffs, sel_g, sel_coef, sel_cnt);
    k7_mask<<<dim3((PHW + 511) / 512, KSPLIT, BB), 128, 0, stream>>>(
        prototypes, gt_masks, sel_coef, sel_g, sel_cnt, acc + 2);
    k8_final<<<1, 1, 0, stream>>>(acc, (int*)(acc + 3), out);
}

// Round 6
// 152.156 us; speedup vs baseline: 4.3839x; 1.2447x over previous
//
#include <hip/hip_runtime.h>
#include <math.h>

#define BB 8
#define AA 19248
#define GG 32
#define CC 81
#define PP 32
#define PHW 19044   /* 138*138 */
#define KPOS 128
#define NEGRATIO 3
#define SELCAP 7680
#define NWCH 304    /* 19 outer iters x 16 waves of 64 anchors */
#define KSPLIT 4
#define KBLK (KPOS / KSPLIT)   /* 32 */

// ---------------------------------------------------------------------------
// IoU helper — contraction off so K1 and K2 produce bitwise-identical values
// and FMA fusion can't flip threshold/argmax decisions vs the XLA reference.
// ---------------------------------------------------------------------------
__device__ __forceinline__ float iou_one(float ax1, float ay1, float ax2, float ay2,
                                         float areaA,
                                         float gx1, float gy1, float gx2, float gy2) {
#pragma clang fp contract(off)
    float ix1 = fmaxf(ax1, gx1), iy1 = fmaxf(ay1, gy1);
    float ix2 = fminf(ax2, gx2), iy2 = fminf(ay2, gy2);
    float iw = fmaxf(ix2 - ix1, 0.0f), ih = fmaxf(iy2 - iy1, 0.0f);
    float inter = iw * ih;
    float areaB = (gx2 - gx1) * (gy2 - gy1);
    float u = areaA + areaB - inter;
    u = fmaxf(u, 1e-6f);
    return inter / u;
}

// ---------------------------------------------------------------------------
// K1: per (b,a) best IoU + first-max argmax over the 32 GT boxes.
// ---------------------------------------------------------------------------
__global__ void k1_best_per_anchor(const float* __restrict__ anchors,
                                   const float* __restrict__ gt_boxes,
                                   float* __restrict__ best_iou,
                                   int* __restrict__ best_g) {
#pragma clang fp contract(off)
    int b = blockIdx.y;
    int a = blockIdx.x * 256 + threadIdx.x;
    __shared__ float sg[GG][4];
    for (int t = threadIdx.x; t < GG * 4; t += 256)
        sg[t >> 2][t & 3] = gt_boxes[b * GG * 4 + t] / 550.0f;
    __syncthreads();
    if (a >= AA) return;
    float4 an = ((const float4*)anchors)[a];
    float ax1 = an.x - an.z * 0.5f, ay1 = an.y - an.w * 0.5f;
    float ax2 = an.x + an.z * 0.5f, ay2 = an.y + an.w * 0.5f;
    float areaA = (ax2 - ax1) * (ay2 - ay1);
    float best = -1.0f; int bi = 0;
    for (int g = 0; g < GG; ++g) {
        float v = iou_one(ax1, ay1, ax2, ay2, areaA, sg[g][0], sg[g][1], sg[g][2], sg[g][3]);
        if (v > best) { best = v; bi = g; }  // strict > keeps FIRST max (jnp.argmax)
    }
    best_iou[b * AA + a] = best;
    best_g[b * AA + a] = bi;
}

// ---------------------------------------------------------------------------
// K2: per (b,g) argmax over all anchors (first occurrence on ties -> packed
// key with inverted index, take max).
// ---------------------------------------------------------------------------
__global__ void k2_best_anchor_per_gt(const float* __restrict__ anchors,
                                      const float* __restrict__ gt_boxes,
                                      int* __restrict__ best_anchor) {
#pragma clang fp contract(off)
    int b = blockIdx.y, g = blockIdx.x;
    float gx1 = gt_boxes[(b * GG + g) * 4 + 0] / 550.0f;
    float gy1 = gt_boxes[(b * GG + g) * 4 + 1] / 550.0f;
    float gx2 = gt_boxes[(b * GG + g) * 4 + 2] / 550.0f;
    float gy2 = gt_boxes[(b * GG + g) * 4 + 3] / 550.0f;
    unsigned long long lk = 0ULL;
    const float4* a4 = (const float4*)anchors;
    for (int a = threadIdx.x; a < AA; a += 256) {
        float4 an = a4[a];
        float ax1 = an.x - an.z * 0.5f, ay1 = an.y - an.w * 0.5f;
        float ax2 = an.x + an.z * 0.5f, ay2 = an.y + an.w * 0.5f;
        float areaA = (ax2 - ax1) * (ay2 - ay1);
        float v = iou_one(ax1, ay1, ax2, ay2, areaA, gx1, gy1, gx2, gy2);
        unsigned long long key =
            ((unsigned long long)__float_as_uint(v) << 32) | (unsigned)(AA - 1 - a);
        if (key > lk) lk = key;
    }
    for (int off = 32; off; off >>= 1) {
        unsigned long long o = __shfl_xor(lk, off);
        if (o > lk) lk = o;
    }
    __shared__ unsigned long long sk[4];
    if ((threadIdx.x & 63) == 0) sk[threadIdx.x >> 6] = lk;
    __syncthreads();
    if (threadIdx.x == 0) {
        unsigned long long m = sk[0];
        for (int i = 1; i < 4; ++i) if (sk[i] > m) m = sk[i];
        best_anchor[b * GG + g] = AA - 1 - (int)(unsigned)(m & 0xffffffffu);
    }
}

// ---------------------------------------------------------------------------
// K3: per image — scatter overrides via an O(1) LDS lookup table (written in
// ascending g by one thread -> last wins, matching XLA scatter), pos
// compaction + keys, hard-negative cap via ballot-based scan, active-row
// compaction. selmask: 0 = unused, 1 = neg, 2 = pos.
// ---------------------------------------------------------------------------
__global__ __launch_bounds__(1024) void k3_match_scan(
    const float* __restrict__ best_iou, const int* __restrict__ best_g_in,
    const int* __restrict__ best_anchor,
    int* __restrict__ gidx_out, int* __restrict__ selmask,
    unsigned long long* __restrict__ pos_key,
    int* __restrict__ pos_cnt, int* __restrict__ g_npos,
    int* __restrict__ act_list, int* __restrict__ act_cnt) {
#pragma clang fp contract(off)
    int b = blockIdx.x;
    int tid = threadIdx.x;
    int lane = tid & 63, wid = tid >> 6;
    __shared__ short s_ov[AA];                  // override g per anchor, -1 none
    __shared__ int sba[GG];
    __shared__ unsigned long long s_pmask[NWCH];
    __shared__ unsigned long long s_nmask[NWCH];
    __shared__ int s_woff[NWCH];
    __shared__ int s_wred[5];
    __shared__ int s_cnt, s_act;
    for (int i = tid; i < AA; i += 1024) s_ov[i] = -1;
    if (tid < GG) sba[tid] = best_anchor[b * GG + tid];
    if (tid == 0) { s_cnt = 0; s_act = 0; }
    __syncthreads();
    if (tid == 0) {
        for (int g = 0; g < GG; ++g) s_ov[sba[g]] = (short)g;  // ascending: last wins
    }
    __syncthreads();

    // pass 1: matching decisions + pos keys + per-wave-chunk ballots
    for (int base = 0; base < AA; base += 1024) {
        int a = base + tid;
        bool p = false, npre = false;
        if (a < AA) {
            float biou = best_iou[b * AA + a];
            int ov = s_ov[a];
            int gi = (ov >= 0) ? ov : best_g_in[b * AA + a];
            p = (biou >= 0.5f) || (ov >= 0);
            npre = (biou < 0.4f) && !p;
            gidx_out[b * AA + a] = gi;
            selmask[b * AA + a] = p ? 2 : (npre ? 1 : 0);
            if (p) {
                int slot = atomicAdd(&s_cnt, 1);
                unsigned vb = __float_as_uint(biou + 1.0f);   // >= 0x3F800000
                unsigned long long key =
                    ((unsigned long long)(vb - 0x3F800000u) << 32) |
                    (unsigned)(AA - 1 - a);
                pos_key[(size_t)b * AA + slot] = key;
            }
        }
        unsigned long long pm = __ballot(p);
        unsigned long long nm = __ballot(npre);
        if (lane == 0) {
            int w = (base >> 6) + wid;
            s_pmask[w] = pm;
            s_nmask[w] = nm;
        }
    }
    __syncthreads();
    int npos = s_cnt;
    if (tid == 0) { pos_cnt[b] = npos; atomicAdd(g_npos, npos); }
    int cap = npos * NEGRATIO;

    // scan 304 chunk counts with 5 waves
    int c = (tid < NWCH) ? __popcll(s_nmask[tid]) : 0;
    int inc = c;
    if (wid < 5) {
        #pragma unroll
        for (int d = 1; d < 64; d <<= 1) {
            int t = __shfl_up(inc, d);
            if (lane >= d) inc += t;
        }
        if (lane == 63) s_wred[wid] = inc;
    }
    __syncthreads();
    if (tid == 0) {
        int run = 0;
        #pragma unroll
        for (int i = 0; i < 5; ++i) { int t = s_wred[i]; s_wred[i] = run; run += t; }
    }
    __syncthreads();
    if (tid < NWCH) s_woff[tid] = inc - c + s_wred[wid];   // exclusive prefix
    __syncthreads();

    // pass 2: drop negs beyond cap, compact active rows (order-free)
    for (int base = 0; base < AA; base += 1024) {
        int a = base + tid;
        int w = (base >> 6) + wid;
        unsigned long long nm = s_nmask[w], pm = s_pmask[w];
        bool npre = (nm >> lane) & 1ULL;
        bool pos  = (pm >> lane) & 1ULL;
        int rank = __popcll(nm & ((1ULL << lane) - 1ULL));
        bool kept = npre && (s_woff[w] + rank + 1 <= cap);
        if (a < AA) {
            if (npre && !kept) selmask[b * AA + a] = 0;
            if (pos || kept) {
                int slot = atomicAdd(&s_act, 1);
                act_list[b * AA + slot] = a;
            }
        }
    }
    __syncthreads();
    if (tid == 0) act_cnt[b] = s_act;
}

// ---------------------------------------------------------------------------
// K45: focal classification + box loss fused over the compacted active list.
// One 64-lane group per row; lane 0 adds the box term for positive rows.
// Per-block LDS reduction -> one atomic per block per accumulator.
// ---------------------------------------------------------------------------
#define K45BLK 128
__global__ __launch_bounds__(256) void k45_cls_box(
    const float* __restrict__ cls_p, const int* __restrict__ gtl,
    const int* __restrict__ gidx, const int* __restrict__ selmask,
    const int* __restrict__ act_list, const int* __restrict__ act_cnt,
    const float* __restrict__ box_p, const float* __restrict__ anchors,
    const float* __restrict__ gt_boxes, float* __restrict__ acc) {
    int b = blockIdx.y;
    int n = act_cnt[b];
    int group = blockIdx.x * 4 + (threadIdx.x >> 6);
    int lane = threadIdx.x & 63;
    float fsum = 0.0f, bsum = 0.0f;
    for (int i = group; i < n; i += K45BLK * 4) {
        int a = act_list[b * AA + i];
        int r = b * AA + a;
        const float* x = cls_p + (size_t)r * CC;
        float e0 = x[lane];
        float e1 = (lane < CC - 64) ? x[64 + lane] : -3.0e38f;
        float m = fmaxf(e0, e1);
        for (int off = 32; off; off >>= 1) m = fmaxf(m, __shfl_xor(m, off));
        float s = expf(e0 - m) + ((lane < CC - 64) ? expf(e1 - m) : 0.0f);
        for (int off = 32; off; off >>= 1) s += __shfl_xor(s, off);
        if (lane == 0) {
            int sm = selmask[r];
            int g = gidx[r];
            int lbl = (sm == 2) ? gtl[b * GG + g] : 0;
            float pt = expf(x[lbl] - m) / s;
            pt = fminf(fmaxf(pt, 1e-6f), 1.0f - 1e-6f);
            float at = (lbl > 0) ? 0.25f : 0.75f;
            float om = 1.0f - pt;
            fsum += at * om * om * (-logf(pt));
            if (sm == 2) {
                float m0 = gt_boxes[(b * GG + g) * 4 + 0] / 550.0f;
                float m1 = gt_boxes[(b * GG + g) * 4 + 1] / 550.0f;
                float m2 = gt_boxes[(b * GG + g) * 4 + 2] / 550.0f;
                float m3 = gt_boxes[(b * GG + g) * 4 + 3] / 550.0f;
                float4 an = ((const float4*)anchors)[a];
                float gcx = 0.5f * (m0 + m2), gcy = 0.5f * (m1 + m3);
                float gw = fmaxf(m2 - m0, 1e-6f), gh = fmaxf(m3 - m1, 1e-6f);
                float t0 = (gcx - an.x) / (an.z * 0.1f);
                float t1 = (gcy - an.y) / (an.w * 0.1f);
                float t2 = logf(gw / an.z) / 0.2f;
                float t3 = logf(gh / an.w) / 0.2f;
                const float* bp = box_p + (size_t)r * 4;
                float d;
                d = fabsf(bp[0] - t0); bsum += (d < 1.0f) ? 0.5f * d * d : d - 0.5f;
                d = fabsf(bp[1] - t1); bsum += (d < 1.0f) ? 0.5f * d * d : d - 0.5f;
                d = fabsf(bp[2] - t2); bsum += (d < 1.0f) ? 0.5f * d * d : d - 0.5f;
                d = fabsf(bp[3] - t3); bsum += (d < 1.0f) ? 0.5f * d * d : d - 0.5f;
            }
        }
    }
    __shared__ float s4f[4], s4b[4];
    if (lane == 0) { s4f[threadIdx.x >> 6] = fsum; s4b[threadIdx.x >> 6] = bsum; }
    __syncthreads();
    if (threadIdx.x == 0) {
        atomicAdd(acc + 0, s4f[0] + s4f[1] + s4f[2] + s4f[3]);
        atomicAdd(acc + 1, s4b[0] + s4b[1] + s4b[2] + s4b[3]);
    }
}

// ---------------------------------------------------------------------------
// K6: per-image top-min(npos,128) via MSB-first radix select on unique 56-bit
// keys, then counting-sort selection by matched gt index g (order within the
// selection is free — commutative sum, all weights 1). Gathers coeffs + g.
// ---------------------------------------------------------------------------
__global__ __launch_bounds__(1024) void k6_select(
    const unsigned long long* __restrict__ pos_key, const int* __restrict__ pos_cnt,
    const int* __restrict__ gidx, const float* __restrict__ coeffs,
    int* __restrict__ sel_g, float* __restrict__ sel_coef, int* __restrict__ sel_cnt) {
    int b = blockIdx.x, tid = threadIdx.x;
    __shared__ unsigned long long s_keys[SELCAP];
    __shared__ int s_hist[256];
    __shared__ int s_sfx[256];
    __shared__ int s_wsum[4];
    __shared__ unsigned long long s_prefix;
    __shared__ int s_kk;
    __shared__ int s_nsel;
    __shared__ int s_sel_a[KPOS];
    __shared__ int s_sorted_a[KPOS];
    __shared__ int s_sorted_g[KPOS];
    __shared__ int s_gcnt[GG];

    int n = pos_cnt[b];
    int K = (n < KPOS) ? n : KPOS;
    const unsigned long long* keys;
    if (n <= SELCAP) {
        for (int i = tid; i < n; i += 1024) s_keys[i] = pos_key[(size_t)b * AA + i];
        keys = s_keys;
    } else {
        keys = pos_key + (size_t)b * AA;
    }
    if (tid == 0) { s_prefix = 0ULL; s_kk = KPOS; s_nsel = 0; }
    __syncthreads();

    if (n > KPOS) {
        for (int d = 6; d >= 0; --d) {
            unsigned long long pref = s_prefix;   // snapshot (post-barrier)
            int kk = s_kk;
            if (tid < 256) s_hist[tid] = 0;
            __syncthreads();
            unsigned long long mhi = ~((1ULL << (8 * (d + 1))) - 1ULL);
            for (int i = tid; i < n; i += 1024) {
                unsigned long long k = keys[i];
                if ((k & mhi) == pref)
                    atomicAdd(&s_hist[(int)((k >> (8 * d)) & 255)], 1);
            }
            __syncthreads();
            int x = 0;
            if (tid < 256) {
                x = s_hist[255 - tid];
                #pragma unroll
                for (int o = 1; o < 64; o <<= 1) {
                    int t = __shfl_up(x, o);
                    if ((tid & 63) >= o) x += t;
                }
                if ((tid & 63) == 63) s_wsum[tid >> 6] = x;
            }
            __syncthreads();
            if (tid == 0) {
                int run = 0;
                #pragma unroll
                for (int i = 0; i < 4; ++i) { int t = s_wsum[i]; s_wsum[i] = run; run += t; }
            }
            __syncthreads();
            if (tid < 256) s_sfx[255 - tid] = x + s_wsum[tid >> 6];
            __syncthreads();
            if (tid < 256) {
                int v = tid;
                int ge = s_sfx[v];
                int gt = (v == 255) ? 0 : s_sfx[v + 1];
                if (ge >= kk && gt < kk) {
                    s_prefix = pref | ((unsigned long long)v << (8 * d));
                    s_kk = kk - gt;
                }
            }
            __syncthreads();
        }
    }

    unsigned long long T = (n > KPOS) ? s_prefix : 0ULL;
    for (int i = tid; i < n; i += 1024) {
        unsigned long long k = keys[i];
        if (k >= T) {
            int slot = atomicAdd(&s_nsel, 1);
            if (slot < KPOS)
                s_sel_a[slot] = AA - 1 - (int)(unsigned)(k & 0xffffffffu);
        }
    }
    __syncthreads();

    if (tid < GG) s_gcnt[tid] = 0;
    __syncthreads();
    int mya = -1, myg = -1;
    if (tid < K) {
        mya = s_sel_a[tid];
        myg = gidx[b * AA + mya];
        atomicAdd(&s_gcnt[myg], 1);
    }
    __syncthreads();
    if (tid == 0) {
        int run = 0;
        for (int g = 0; g < GG; ++g) { int c = s_gcnt[g]; s_gcnt[g] = run; run += c; }
    }
    __syncthreads();
    if (tid < K) {
        int pos = atomicAdd(&s_gcnt[myg], 1);
        s_sorted_a[pos] = mya;
        s_sorted_g[pos] = myg;
    }
    __syncthreads();

    if (tid == 0) sel_cnt[b] = K;
    for (int t = tid; t < K * PP; t += 1024) {
        int k = t >> 5, p = t & 31;
        int a = s_sorted_a[k];
        sel_coef[(b * KPOS + k) * PP + p] = coeffs[((size_t)(b * AA + a)) * PP + p];
    }
    for (int t = tid; t < K; t += 1024)
        sel_g[b * KPOS + t] = s_sorted_g[t];
}

// ---------------------------------------------------------------------------
// K7: mask loss. 4 px/thread (float4); 256-thread blocks; KSPLIT=4 K-blocks
// of 32 k's -> 608 blocks x 4 waves (occupancy fix for round-5's 10.6%).
// Single-k loop body keeps <=32 live coeff VGPRs so protos stay register-
// resident (round-5 regression: compiler evicted pr[] at VGPR=112). Two
// accumulator chains; g-sorted gt reload; fast __expf/__logf BCE.
// ---------------------------------------------------------------------------
__device__ __forceinline__ float4 fma4(float s, float4 p, float4 a) {
    a.x += s * p.x; a.y += s * p.y; a.z += s * p.z; a.w += s * p.w;
    return a;
}
__device__ __forceinline__ float4 add4(float4 a, float4 b) {
    a.x += b.x; a.y += b.y; a.z += b.z; a.w += b.w;
    return a;
}
__device__ __forceinline__ float4 bce4(float4 l, float4 t, float4 a) {
    a.x += fmaxf(l.x, 0.f) - l.x * t.x + __logf(1.f + __expf(-fabsf(l.x)));
    a.y += fmaxf(l.y, 0.f) - l.y * t.y + __logf(1.f + __expf(-fabsf(l.y)));
    a.z += fmaxf(l.z, 0.f) - l.z * t.z + __logf(1.f + __expf(-fabsf(l.z)));
    a.w += fmaxf(l.w, 0.f) - l.w * t.w + __logf(1.f + __expf(-fabsf(l.w)));
    return a;
}

__global__ __launch_bounds__(256) void k7_mask(
    const float* __restrict__ protos, const float* __restrict__ gtm,
    const float* __restrict__ sel_coef, const int* __restrict__ sel_g,
    const int* __restrict__ sel_cnt, float* __restrict__ acc_mask) {
    int b = blockIdx.z;
    int nk = sel_cnt[b];
    int k0 = blockIdx.y * KBLK;
    if (k0 >= nk) return;                       // uniform early-exit, pre-barrier
    int nkb = min(nk, k0 + KBLK) - k0;
    int tid = threadIdx.x;
    int pix0 = (blockIdx.x * 256 + tid) * 4;

    __shared__ float s_c[KBLK * PP];
    __shared__ int s_g[KBLK];
    __shared__ float s_red[4];
    for (int t = tid; t < nkb * PP; t += 256)
        s_c[t] = sel_coef[(b * KPOS + k0) * PP + t];
    for (int t = tid; t < nkb; t += 256)
        s_g[t] = sel_g[b * KPOS + k0 + t];
    __syncthreads();

    bool valid = pix0 < PHW;
    int pc = valid ? pix0 : 0;
    float4 pr[PP];
    #pragma unroll
    for (int p = 0; p < PP; ++p)
        pr[p] = *(const float4*)&protos[((size_t)(b * PP + p)) * PHW + pc];
    const float* gtm_b = gtm + (size_t)b * GG * PHW + pc;

    float4 acc4 = make_float4(0.f, 0.f, 0.f, 0.f);
    float4 t4 = make_float4(0.f, 0.f, 0.f, 0.f);
    int gprev = -1;
    for (int k = 0; k < nkb; ++k) {
        const float4* c = (const float4*)&s_c[k * PP];
        float4 a0 = make_float4(0.f, 0.f, 0.f, 0.f), b0 = a0;
        #pragma unroll
        for (int q = 0; q < 4; ++q) {
            float4 u = c[q];
            a0 = fma4(u.x, pr[4 * q + 0], a0); b0 = fma4(u.y, pr[4 * q + 1], b0);
            a0 = fma4(u.z, pr[4 * q + 2], a0); b0 = fma4(u.w, pr[4 * q + 3], b0);
        }
        #pragma unroll
        for (int q = 4; q < 8; ++q) {
            float4 u = c[q];
            a0 = fma4(u.x, pr[4 * q + 0], a0); b0 = fma4(u.y, pr[4 * q + 1], b0);
            a0 = fma4(u.z, pr[4 * q + 2], a0); b0 = fma4(u.w, pr[4 * q + 3], b0);
        }
        float4 l = add4(a0, b0);
        int g0 = s_g[k];
        if (g0 != gprev) { t4 = *(const float4*)&gtm_b[(size_t)g0 * PHW]; gprev = g0; }
        acc4 = bce4(l, t4, acc4);
    }

    float acc = valid ? (acc4.x + acc4.y + acc4.z + acc4.w) : 0.0f;
    for (int off = 32; off; off >>= 1) acc += __shfl_xor(acc, off);
    if ((tid & 63) == 0) s_red[tid >> 6] = acc;
    __syncthreads();
    if (tid == 0)
        atomicAdd(acc_mask, s_red[0] + s_red[1] + s_red[2] + s_red[3]);
}

// ---------------------------------------------------------------------------
// K8: finalize.
// ---------------------------------------------------------------------------
__global__ void k8_final(const float* __restrict__ acc, const int* __restrict__ npos,
                         float* __restrict__ out) {
    float denom = fmaxf((float)(*npos), 1.0f);
    out[0] = (1.0f * acc[0] + 1.5f * acc[1] + 6.125f * (acc[2] / (float)PHW)) / denom;
}

// ---------------------------------------------------------------------------
extern "C" void kernel_launch(void* const* d_in, const int* in_sizes, int n_in,
                              void* d_out, int out_size, void* d_ws, size_t ws_size,
                              hipStream_t stream) {
    (void)in_sizes; (void)n_in; (void)out_size; (void)ws_size;
    const float* class_preds = (const float*)d_in[0];
    const float* box_preds   = (const float*)d_in[1];
    const float* mask_coeffs = (const float*)d_in[2];
    const float* prototypes  = (const float*)d_in[3];
    const float* anchors     = (const float*)d_in[4];
    const float* gt_boxes    = (const float*)d_in[5];
    const int*   gt_labels   = (const int*)d_in[6];
    const float* gt_masks    = (const float*)d_in[7];
    float* out = (float*)d_out;

    size_t off = 0;
    char* w = (char*)d_ws;
    auto take = [&](size_t bytes) -> char* {
        char* p = w + off;
        off += (bytes + 255) & ~(size_t)255;
        return p;
    };
    float* acc      = (float*)take(32);                       // [cls, box, mask, npos(int)]
    float* best_iou = (float*)take((size_t)BB * AA * 4);
    int*   best_g   = (int*)  take((size_t)BB * AA * 4);
    int*   gidx     = (int*)  take((size_t)BB * AA * 4);
    int*   selmask  = (int*)  take((size_t)BB * AA * 4);
    int*   banchor  = (int*)  take((size_t)BB * GG * 4);
    int*   pos_cnt  = (int*)  take((size_t)BB * 4);
    unsigned long long* pos_key = (unsigned long long*)take((size_t)BB * AA * 8);
    int*   sel_g    = (int*)  take((size_t)BB * KPOS * 4);
    int*   sel_cnt  = (int*)  take((size_t)BB * 4);
    float* sel_coef = (float*)take((size_t)BB * KPOS * PP * 4);
    int*   act_list = (int*)  take((size_t)BB * AA * 4);
    int*   act_cnt  = (int*)  take((size_t)BB * 4);

    hipMemsetAsync(acc, 0, 32, stream);

    k1_best_per_anchor<<<dim3((AA + 255) / 256, BB), 256, 0, stream>>>(
        anchors, gt_boxes, best_iou, best_g);
    k2_best_anchor_per_gt<<<dim3(GG, BB), 256, 0, stream>>>(
        anchors, gt_boxes, banchor);
    k3_match_scan<<<BB, 1024, 0, stream>>>(
        best_iou, best_g, banchor, gidx, selmask, pos_key, pos_cnt, (int*)(acc + 3),
        act_list, act_cnt);
    k45_cls_box<<<dim3(K45BLK, BB), 256, 0, stream>>>(
        class_preds, gt_labels, gidx, selmask, act_list, act_cnt,
        box_preds, anchors, gt_boxes, acc);
    k6_select<<<BB, 1024, 0, stream>>>(
        pos_key, pos_cnt, gidx, mask_coeffs, sel_g, sel_coef, sel_cnt);
    k7_mask<<<dim3((PHW + 1023) / 1024, KSPLIT, BB), 256, 0, stream>>>(
        prototypes, gt_masks, sel_coef, sel_g, sel_cnt, acc + 2);
    k8_final<<<1, 1, 0, stream>>>(acc, (int*)(acc + 3), out);
}

// Round 7
// 132.173 us; speedup vs baseline: 5.0467x; 1.1512x over previous
//
#include <hip/hip_runtime.h>
#include <math.h>

#define BB 8
#define AA 19248
#define GG 32
#define CC 81
#define PP 32
#define PHW 19044   /* 138*138 */
#define KPOS 128
#define NEGRATIO 3
#define SELCAP 7680
#define NWCH 304    /* 19 outer iters x 16 waves of 64 anchors */
#define KSPLIT 4
#define KBLK (KPOS / KSPLIT)   /* 32 */

// ---------------------------------------------------------------------------
// IoU helper — contraction off so every recomputation produces bitwise-
// identical values and FMA fusion can't flip threshold/argmax decisions.
// ---------------------------------------------------------------------------
__device__ __forceinline__ float iou_one(float ax1, float ay1, float ax2, float ay2,
                                         float areaA,
                                         float gx1, float gy1, float gx2, float gy2) {
#pragma clang fp contract(off)
    float ix1 = fmaxf(ax1, gx1), iy1 = fmaxf(ay1, gy1);
    float ix2 = fminf(ax2, gx2), iy2 = fminf(ay2, gy2);
    float iw = fmaxf(ix2 - ix1, 0.0f), ih = fmaxf(iy2 - iy1, 0.0f);
    float inter = iw * ih;
    float areaB = (gx2 - gx1) * (gy2 - gy1);
    float u = areaA + areaB - inter;
    u = fmaxf(u, 1e-6f);
    return inter / u;
}

// ---------------------------------------------------------------------------
// K1 (fused with old K2): per (b,a) best IoU + first-max argmax over g, AND
// per (b,g) best-anchor via lane-staggered LDS atomicMax on packed keys
// (value desc, index asc -> first-occurrence argmax like jnp.argmax axis=0),
// finished with 32 global atomicMax per block. IoU computed ONCE per (b,a,g).
// ---------------------------------------------------------------------------
__global__ __launch_bounds__(256) void k1_match(
    const float* __restrict__ anchors, const float* __restrict__ gt_boxes,
    float* __restrict__ best_iou, int* __restrict__ best_g,
    unsigned long long* __restrict__ gkey) {
#pragma clang fp contract(off)
    int b = blockIdx.y;
    int a = blockIdx.x * 256 + threadIdx.x;
    int lane = threadIdx.x & 63;
    __shared__ float sg[GG][4];
    __shared__ unsigned long long s_gk[GG];
    for (int t = threadIdx.x; t < GG * 4; t += 256)
        sg[t >> 2][t & 3] = gt_boxes[b * GG * 4 + t] / 550.0f;
    if (threadIdx.x < GG) s_gk[threadIdx.x] = 0ULL;
    __syncthreads();
    bool valid = a < AA;
    int ac = valid ? a : AA - 1;
    float4 an = ((const float4*)anchors)[ac];
    float ax1 = an.x - an.z * 0.5f, ay1 = an.y - an.w * 0.5f;
    float ax2 = an.x + an.z * 0.5f, ay2 = an.y + an.w * 0.5f;
    float areaA = (ax2 - ax1) * (ay2 - ay1);
    unsigned long long bk = 0ULL;   // (vbits<<6)|(31-g): max => first-max argmax
    for (int gg = 0; gg < GG; ++gg) {
        int g = (gg + lane) & (GG - 1);          // stagger: 32 distinct LDS slots
        float v = iou_one(ax1, ay1, ax2, ay2, areaA, sg[g][0], sg[g][1], sg[g][2], sg[g][3]);
        unsigned vb = __float_as_uint(v);        // v >= 0 -> order-preserving
        unsigned long long k2 = ((unsigned long long)vb << 6) | (unsigned)(GG - 1 - g);
        if (k2 > bk) bk = k2;
        if (valid) {
            unsigned long long kg =
                ((unsigned long long)vb << 32) | (unsigned)(AA - 1 - a);
            atomicMax(&s_gk[g], kg);
        }
    }
    if (valid) {
        best_iou[b * AA + a] = __uint_as_float((unsigned)(bk >> 6));
        best_g[b * AA + a] = (GG - 1) - (int)(bk & 63ULL);
    }
    __syncthreads();
    if (threadIdx.x < GG)
        atomicMax(&gkey[b * GG + threadIdx.x], s_gk[threadIdx.x]);
}

// ---------------------------------------------------------------------------
// K3: per image — scatter overrides via an O(1) LDS lookup table (written in
// ascending g by one thread -> last wins, matching XLA scatter), pos
// compaction + keys, hard-negative cap via ballot-based scan, active-row
// compaction. selmask: 0 = unused, 1 = neg, 2 = pos.
// ---------------------------------------------------------------------------
__global__ __launch_bounds__(1024) void k3_match_scan(
    const float* __restrict__ best_iou, const int* __restrict__ best_g_in,
    const unsigned long long* __restrict__ gkey,
    int* __restrict__ gidx_out, int* __restrict__ selmask,
    unsigned long long* __restrict__ pos_key,
    int* __restrict__ pos_cnt, int* __restrict__ g_npos,
    int* __restrict__ act_list, int* __restrict__ act_cnt) {
#pragma clang fp contract(off)
    int b = blockIdx.x;
    int tid = threadIdx.x;
    int lane = tid & 63, wid = tid >> 6;
    __shared__ short s_ov[AA];                  // override g per anchor, -1 none
    __shared__ int sba[GG];
    __shared__ unsigned long long s_pmask[NWCH];
    __shared__ unsigned long long s_nmask[NWCH];
    __shared__ int s_woff[NWCH];
    __shared__ int s_wred[5];
    __shared__ int s_cnt, s_act;
    for (int i = tid; i < AA; i += 1024) s_ov[i] = -1;
    if (tid < GG)
        sba[tid] = AA - 1 - (int)(unsigned)(gkey[b * GG + tid] & 0xffffffffULL);
    if (tid == 0) { s_cnt = 0; s_act = 0; }
    __syncthreads();
    if (tid == 0) {
        for (int g = 0; g < GG; ++g) s_ov[sba[g]] = (short)g;  // ascending: last wins
    }
    __syncthreads();

    // pass 1: matching decisions + pos keys + per-wave-chunk ballots
    for (int base = 0; base < AA; base += 1024) {
        int a = base + tid;
        bool p = false, npre = false;
        if (a < AA) {
            float biou = best_iou[b * AA + a];
            int ov = s_ov[a];
            int gi = (ov >= 0) ? ov : best_g_in[b * AA + a];
            p = (biou >= 0.5f) || (ov >= 0);
            npre = (biou < 0.4f) && !p;
            gidx_out[b * AA + a] = gi;
            selmask[b * AA + a] = p ? 2 : (npre ? 1 : 0);
            if (p) {
                int slot = atomicAdd(&s_cnt, 1);
                unsigned vb = __float_as_uint(biou + 1.0f);   // >= 0x3F800000
                unsigned long long key =
                    ((unsigned long long)(vb - 0x3F800000u) << 32) |
                    (unsigned)(AA - 1 - a);
                pos_key[(size_t)b * AA + slot] = key;
            }
        }
        unsigned long long pm = __ballot(p);
        unsigned long long nm = __ballot(npre);
        if (lane == 0) {
            int w = (base >> 6) + wid;
            s_pmask[w] = pm;
            s_nmask[w] = nm;
        }
    }
    __syncthreads();
    int npos = s_cnt;
    if (tid == 0) { pos_cnt[b] = npos; atomicAdd(g_npos, npos); }
    int cap = npos * NEGRATIO;

    // scan 304 chunk counts with 5 waves
    int c = (tid < NWCH) ? __popcll(s_nmask[tid]) : 0;
    int inc = c;
    if (wid < 5) {
        #pragma unroll
        for (int d = 1; d < 64; d <<= 1) {
            int t = __shfl_up(inc, d);
            if (lane >= d) inc += t;
        }
        if (lane == 63) s_wred[wid] = inc;
    }
    __syncthreads();
    if (tid == 0) {
        int run = 0;
        #pragma unroll
        for (int i = 0; i < 5; ++i) { int t = s_wred[i]; s_wred[i] = run; run += t; }
    }
    __syncthreads();
    if (tid < NWCH) s_woff[tid] = inc - c + s_wred[wid];   // exclusive prefix
    __syncthreads();

    // pass 2: drop negs beyond cap, compact active rows (order-free)
    for (int base = 0; base < AA; base += 1024) {
        int a = base + tid;
        int w = (base >> 6) + wid;
        unsigned long long nm = s_nmask[w], pm = s_pmask[w];
        bool npre = (nm >> lane) & 1ULL;
        bool pos  = (pm >> lane) & 1ULL;
        int rank = __popcll(nm & ((1ULL << lane) - 1ULL));
        bool kept = npre && (s_woff[w] + rank + 1 <= cap);
        if (a < AA) {
            if (npre && !kept) selmask[b * AA + a] = 0;
            if (pos || kept) {
                int slot = atomicAdd(&s_act, 1);
                act_list[b * AA + slot] = a;
            }
        }
    }
    __syncthreads();
    if (tid == 0) act_cnt[b] = s_act;
}

// ---------------------------------------------------------------------------
// K45: focal classification + box loss fused over the compacted active list.
// One 64-lane group per row; lane 0 adds the box term for positive rows.
// Per-block LDS reduction -> one atomic per block per accumulator.
// ---------------------------------------------------------------------------
#define K45BLK 128
__global__ __launch_bounds__(256) void k45_cls_box(
    const float* __restrict__ cls_p, const int* __restrict__ gtl,
    const int* __restrict__ gidx, const int* __restrict__ selmask,
    const int* __restrict__ act_list, const int* __restrict__ act_cnt,
    const float* __restrict__ box_p, const float* __restrict__ anchors,
    const float* __restrict__ gt_boxes, float* __restrict__ acc) {
    int b = blockIdx.y;
    int n = act_cnt[b];
    int group = blockIdx.x * 4 + (threadIdx.x >> 6);
    int lane = threadIdx.x & 63;
    float fsum = 0.0f, bsum = 0.0f;
    for (int i = group; i < n; i += K45BLK * 4) {
        int a = act_list[b * AA + i];
        int r = b * AA + a;
        const float* x = cls_p + (size_t)r * CC;
        float e0 = x[lane];
        float e1 = (lane < CC - 64) ? x[64 + lane] : -3.0e38f;
        float m = fmaxf(e0, e1);
        for (int off = 32; off; off >>= 1) m = fmaxf(m, __shfl_xor(m, off));
        float s = expf(e0 - m) + ((lane < CC - 64) ? expf(e1 - m) : 0.0f);
        for (int off = 32; off; off >>= 1) s += __shfl_xor(s, off);
        if (lane == 0) {
            int sm = selmask[r];
            int g = gidx[r];
            int lbl = (sm == 2) ? gtl[b * GG + g] : 0;
            float pt = expf(x[lbl] - m) / s;
            pt = fminf(fmaxf(pt, 1e-6f), 1.0f - 1e-6f);
            float at = (lbl > 0) ? 0.25f : 0.75f;
            float om = 1.0f - pt;
            fsum += at * om * om * (-logf(pt));
            if (sm == 2) {
                float m0 = gt_boxes[(b * GG + g) * 4 + 0] / 550.0f;
                float m1 = gt_boxes[(b * GG + g) * 4 + 1] / 550.0f;
                float m2 = gt_boxes[(b * GG + g) * 4 + 2] / 550.0f;
                float m3 = gt_boxes[(b * GG + g) * 4 + 3] / 550.0f;
                float4 an = ((const float4*)anchors)[a];
                float gcx = 0.5f * (m0 + m2), gcy = 0.5f * (m1 + m3);
                float gw = fmaxf(m2 - m0, 1e-6f), gh = fmaxf(m3 - m1, 1e-6f);
                float t0 = (gcx - an.x) / (an.z * 0.1f);
                float t1 = (gcy - an.y) / (an.w * 0.1f);
                float t2 = logf(gw / an.z) / 0.2f;
                float t3 = logf(gh / an.w) / 0.2f;
                const float* bp = box_p + (size_t)r * 4;
                float d;
                d = fabsf(bp[0] - t0); bsum += (d < 1.0f) ? 0.5f * d * d : d - 0.5f;
                d = fabsf(bp[1] - t1); bsum += (d < 1.0f) ? 0.5f * d * d : d - 0.5f;
                d = fabsf(bp[2] - t2); bsum += (d < 1.0f) ? 0.5f * d * d : d - 0.5f;
                d = fabsf(bp[3] - t3); bsum += (d < 1.0f) ? 0.5f * d * d : d - 0.5f;
            }
        }
    }
    __shared__ float s4f[4], s4b[4];
    if (lane == 0) { s4f[threadIdx.x >> 6] = fsum; s4b[threadIdx.x >> 6] = bsum; }
    __syncthreads();
    if (threadIdx.x == 0) {
        atomicAdd(acc + 0, s4f[0] + s4f[1] + s4f[2] + s4f[3]);
        atomicAdd(acc + 1, s4b[0] + s4b[1] + s4b[2] + s4b[3]);
    }
}

// ---------------------------------------------------------------------------
// K6: per-image top-min(npos,128) via MSB-first radix select on unique 56-bit
// keys, then counting-sort selection by matched gt index g (order within the
// selection is free — commutative sum, all weights 1). Gathers coeffs + g.
// ---------------------------------------------------------------------------
__global__ __launch_bounds__(1024) void k6_select(
    const unsigned long long* __restrict__ pos_key, const int* __restrict__ pos_cnt,
    const int* __restrict__ gidx, const float* __restrict__ coeffs,
    int* __restrict__ sel_g, float* __restrict__ sel_coef, int* __restrict__ sel_cnt) {
    int b = blockIdx.x, tid = threadIdx.x;
    __shared__ unsigned long long s_keys[SELCAP];
    __shared__ int s_hist[256];
    __shared__ int s_sfx[256];
    __shared__ int s_wsum[4];
    __shared__ unsigned long long s_prefix;
    __shared__ int s_kk;
    __shared__ int s_nsel;
    __shared__ int s_sel_a[KPOS];
    __shared__ int s_sorted_a[KPOS];
    __shared__ int s_sorted_g[KPOS];
    __shared__ int s_gcnt[GG];

    int n = pos_cnt[b];
    int K = (n < KPOS) ? n : KPOS;
    const unsigned long long* keys;
    if (n <= SELCAP) {
        for (int i = tid; i < n; i += 1024) s_keys[i] = pos_key[(size_t)b * AA + i];
        keys = s_keys;
    } else {
        keys = pos_key + (size_t)b * AA;
    }
    if (tid == 0) { s_prefix = 0ULL; s_kk = KPOS; s_nsel = 0; }
    __syncthreads();

    if (n > KPOS) {
        for (int d = 6; d >= 0; --d) {
            unsigned long long pref = s_prefix;   // snapshot (post-barrier)
            int kk = s_kk;
            if (tid < 256) s_hist[tid] = 0;
            __syncthreads();
            unsigned long long mhi = ~((1ULL << (8 * (d + 1))) - 1ULL);
            for (int i = tid; i < n; i += 1024) {
                unsigned long long k = keys[i];
                if ((k & mhi) == pref)
                    atomicAdd(&s_hist[(int)((k >> (8 * d)) & 255)], 1);
            }
            __syncthreads();
            int x = 0;
            if (tid < 256) {
                x = s_hist[255 - tid];
                #pragma unroll
                for (int o = 1; o < 64; o <<= 1) {
                    int t = __shfl_up(x, o);
                    if ((tid & 63) >= o) x += t;
                }
                if ((tid & 63) == 63) s_wsum[tid >> 6] = x;
            }
            __syncthreads();
            if (tid == 0) {
                int run = 0;
                #pragma unroll
                for (int i = 0; i < 4; ++i) { int t = s_wsum[i]; s_wsum[i] = run; run += t; }
            }
            __syncthreads();
            if (tid < 256) s_sfx[255 - tid] = x + s_wsum[tid >> 6];
            __syncthreads();
            if (tid < 256) {
                int v = tid;
                int ge = s_sfx[v];
                int gt = (v == 255) ? 0 : s_sfx[v + 1];
                if (ge >= kk && gt < kk) {
                    s_prefix = pref | ((unsigned long long)v << (8 * d));
                    s_kk = kk - gt;
                }
            }
            __syncthreads();
        }
    }

    unsigned long long T = (n > KPOS) ? s_prefix : 0ULL;
    for (int i = tid; i < n; i += 1024) {
        unsigned long long k = keys[i];
        if (k >= T) {
            int slot = atomicAdd(&s_nsel, 1);
            if (slot < KPOS)
                s_sel_a[slot] = AA - 1 - (int)(unsigned)(k & 0xffffffffu);
        }
    }
    __syncthreads();

    if (tid < GG) s_gcnt[tid] = 0;
    __syncthreads();
    int mya = -1, myg = -1;
    if (tid < K) {
        mya = s_sel_a[tid];
        myg = gidx[b * AA + mya];
        atomicAdd(&s_gcnt[myg], 1);
    }
    __syncthreads();
    if (tid == 0) {
        int run = 0;
        for (int g = 0; g < GG; ++g) { int c = s_gcnt[g]; s_gcnt[g] = run; run += c; }
    }
    __syncthreads();
    if (tid < K) {
        int pos = atomicAdd(&s_gcnt[myg], 1);
        s_sorted_a[pos] = mya;
        s_sorted_g[pos] = myg;
    }
    __syncthreads();

    if (tid == 0) sel_cnt[b] = K;
    for (int t = tid; t < K * PP; t += 1024) {
        int k = t >> 5, p = t & 31;
        int a = s_sorted_a[k];
        sel_coef[(b * KPOS + k) * PP + p] = coeffs[((size_t)(b * AA + a)) * PP + p];
    }
    for (int t = tid; t < K; t += 1024)
        sel_g[b * KPOS + t] = s_sorted_g[t];
}

// ---------------------------------------------------------------------------
// K7: mask loss. 4 px/thread (float4); KSPLIT=4 K-blocks of 32 k's.
// __launch_bounds__(256, 2): min 2 waves/SIMD -> VGPR cap 256, so the 128-VGPR
// proto tile STAYS register-resident (rounds 5/6 regression: default heuristic
// spilled pr[] at VGPR 92-112 and re-read protos from L2 every k). 8 waves/CU
// hide the 8 independent ds_read_b128 per k under the 128 FMAs.
// ---------------------------------------------------------------------------
__device__ __forceinline__ float4 fma4(float s, float4 p, float4 a) {
    a.x += s * p.x; a.y += s * p.y; a.z += s * p.z; a.w += s * p.w;
    return a;
}
__device__ __forceinline__ float4 add4(float4 a, float4 b) {
    a.x += b.x; a.y += b.y; a.z += b.z; a.w += b.w;
    return a;
}
__device__ __forceinline__ float4 bce4(float4 l, float4 t, float4 a) {
    a.x += fmaxf(l.x, 0.f) - l.x * t.x + __logf(1.f + __expf(-fabsf(l.x)));
    a.y += fmaxf(l.y, 0.f) - l.y * t.y + __logf(1.f + __expf(-fabsf(l.y)));
    a.z += fmaxf(l.z, 0.f) - l.z * t.z + __logf(1.f + __expf(-fabsf(l.z)));
    a.w += fmaxf(l.w, 0.f) - l.w * t.w + __logf(1.f + __expf(-fabsf(l.w)));
    return a;
}

__global__ __launch_bounds__(256, 2) void k7_mask(
    const float* __restrict__ protos, const float* __restrict__ gtm,
    const float* __restrict__ sel_coef, const int* __restrict__ sel_g,
    const int* __restrict__ sel_cnt, float* __restrict__ acc_mask) {
    int b = blockIdx.z;
    int nk = sel_cnt[b];
    int k0 = blockIdx.y * KBLK;
    if (k0 >= nk) return;                       // uniform early-exit, pre-barrier
    int nkb = min(nk, k0 + KBLK) - k0;
    int tid = threadIdx.x;
    int pix0 = (blockIdx.x * 256 + tid) * 4;

    __shared__ float s_c[KBLK * PP];
    __shared__ int s_g[KBLK];
    __shared__ float s_red[4];
    for (int t = tid; t < nkb * PP; t += 256)
        s_c[t] = sel_coef[(b * KPOS + k0) * PP + t];
    for (int t = tid; t < nkb; t += 256)
        s_g[t] = sel_g[b * KPOS + k0 + t];
    __syncthreads();

    bool valid = pix0 < PHW;
    int pc = valid ? pix0 : 0;
    float4 pr[PP];
    #pragma unroll
    for (int p = 0; p < PP; ++p)
        pr[p] = *(const float4*)&protos[((size_t)(b * PP + p)) * PHW + pc];
    const float* gtm_b = gtm + (size_t)b * GG * PHW + pc;

    float4 acc4 = make_float4(0.f, 0.f, 0.f, 0.f);
    float4 t4 = make_float4(0.f, 0.f, 0.f, 0.f);
    int gprev = -1;
    for (int k = 0; k < nkb; ++k) {
        const float4* c = (const float4*)&s_c[k * PP];
        float4 a0 = make_float4(0.f, 0.f, 0.f, 0.f), b0 = a0;
        #pragma unroll
        for (int q = 0; q < 8; ++q) {
            float4 u = c[q];
            a0 = fma4(u.x, pr[4 * q + 0], a0); b0 = fma4(u.y, pr[4 * q + 1], b0);
            a0 = fma4(u.z, pr[4 * q + 2], a0); b0 = fma4(u.w, pr[4 * q + 3], b0);
        }
        float4 l = add4(a0, b0);
        int g0 = s_g[k];
        if (g0 != gprev) { t4 = *(const float4*)&gtm_b[(size_t)g0 * PHW]; gprev = g0; }
        acc4 = bce4(l, t4, acc4);
    }

    float acc = valid ? (acc4.x + acc4.y + acc4.z + acc4.w) : 0.0f;
    for (int off = 32; off; off >>= 1) acc += __shfl_xor(acc, off);
    if ((tid & 63) == 0) s_red[tid >> 6] = acc;
    __syncthreads();
    if (tid == 0)
        atomicAdd(acc_mask, s_red[0] + s_red[1] + s_red[2] + s_red[3]);
}

// ---------------------------------------------------------------------------
// K8: finalize.
// ---------------------------------------------------------------------------
__global__ void k8_final(const float* __restrict__ acc, const int* __restrict__ npos,
                         float* __restrict__ out) {
    float denom = fmaxf((float)(*npos), 1.0f);
    out[0] = (1.0f * acc[0] + 1.5f * acc[1] + 6.125f * (acc[2] / (float)PHW)) / denom;
}

// ---------------------------------------------------------------------------
extern "C" void kernel_launch(void* const* d_in, const int* in_sizes, int n_in,
                              void* d_out, int out_size, void* d_ws, size_t ws_size,
                              hipStream_t stream) {
    (void)in_sizes; (void)n_in; (void)out_size; (void)ws_size;
    const float* class_preds = (const float*)d_in[0];
    const float* box_preds   = (const float*)d_in[1];
    const float* mask_coeffs = (const float*)d_in[2];
    const float* prototypes  = (const float*)d_in[3];
    const float* anchors     = (const float*)d_in[4];
    const float* gt_boxes    = (const float*)d_in[5];
    const int*   gt_labels   = (const int*)d_in[6];
    const float* gt_masks    = (const float*)d_in[7];
    float* out = (float*)d_out;

    size_t off = 0;
    char* w = (char*)d_ws;
    auto take = [&](size_t bytes) -> char* {
        char* p = w + off;
        off += (bytes + 255) & ~(size_t)255;
        return p;
    };
    float* acc      = (float*)take(32);                       // [cls, box, mask, npos(int)]
    float* best_iou = (float*)take((size_t)BB * AA * 4);
    int*   best_g   = (int*)  take((size_t)BB * AA * 4);
    int*   gidx     = (int*)  take((size_t)BB * AA * 4);
    int*   selmask  = (int*)  take((size_t)BB * AA * 4);
    unsigned long long* gkey = (unsigned long long*)take((size_t)BB * GG * 8);
    int*   pos_cnt  = (int*)  take((size_t)BB * 4);
    unsigned long long* pos_key = (unsigned long long*)take((size_t)BB * AA * 8);
    int*   sel_g    = (int*)  take((size_t)BB * KPOS * 4);
    int*   sel_cnt  = (int*)  take((size_t)BB * 4);
    float* sel_coef = (float*)take((size_t)BB * KPOS * PP * 4);
    int*   act_list = (int*)  take((size_t)BB * AA * 4);
    int*   act_cnt  = (int*)  take((size_t)BB * 4);

    hipMemsetAsync(acc, 0, 32, stream);
    hipMemsetAsync(gkey, 0, (size_t)BB * GG * 8, stream);

    k1_match<<<dim3((AA + 255) / 256, BB), 256, 0, stream>>>(
        anchors, gt_boxes, best_iou, best_g, gkey);
    k3_match_scan<<<BB, 1024, 0, stream>>>(
        best_iou, best_g, gkey, gidx, selmask, pos_key, pos_cnt, (int*)(acc + 3),
        act_list, act_cnt);
    k45_cls_box<<<dim3(K45BLK, BB), 256, 0, stream>>>(
        class_preds, gt_labels, gidx, selmask, act_list, act_cnt,
        box_preds, anchors, gt_boxes, acc);
    k6_select<<<BB, 1024, 0, stream>>>(
        pos_key, pos_cnt, gidx, mask_coeffs, sel_g, sel_coef, sel_cnt);
    k7_mask<<<dim3((PHW + 1023) / 1024, KSPLIT, BB), 256, 0, stream>>>(
        prototypes, gt_masks, sel_coef, sel_g, sel_cnt, acc + 2);
    k8_final<<<1, 1, 0, stream>>>(acc, (int*)(acc + 3), out);
}

// Round 8
// 124.081 us; speedup vs baseline: 5.3759x; 1.0652x over previous
//
#include <hip/hip_runtime.h>
#include <math.h>

#define BB 8
#define AA 19248
#define GG 32
#define CC 81
#define PP 32
#define PHW 19044   /* 138*138 */
#define KPOS 128
#define NEGRATIO 3
#define SELCAP 7680
#define NWCH 304    /* 19 outer iters x 16 waves of 64 anchors */
#define NB1 76      /* k1 blocks per image = ceil(AA/256) */
#define KSPLIT 8
#define KBLK (KPOS / KSPLIT)   /* 16 */

// ---------------------------------------------------------------------------
// IoU helper — contraction off so every recomputation produces bitwise-
// identical values and FMA fusion can't flip threshold/argmax decisions.
// ---------------------------------------------------------------------------
__device__ __forceinline__ float iou_one(float ax1, float ay1, float ax2, float ay2,
                                         float areaA,
                                         float gx1, float gy1, float gx2, float gy2) {
#pragma clang fp contract(off)
    float ix1 = fmaxf(ax1, gx1), iy1 = fmaxf(ay1, gy1);
    float ix2 = fminf(ax2, gx2), iy2 = fminf(ay2, gy2);
    float iw = fmaxf(ix2 - ix1, 0.0f), ih = fmaxf(iy2 - iy1, 0.0f);
    float inter = iw * ih;
    float areaB = (gx2 - gx1) * (gy2 - gy1);
    float u = areaA + areaB - inter;
    u = fmaxf(u, 1e-6f);
    return inter / u;
}

// ---------------------------------------------------------------------------
// K1: per (b,a) best IoU + first-max argmax over g, AND per-(b,g) best-anchor
// partial keys per block (value desc, index asc), reduced in K3 — no global
// atomics, no memset needed. Block (0,0) also zeroes the 4 accumulators
// (stream-ordered before every consumer kernel).
// ---------------------------------------------------------------------------
__global__ __launch_bounds__(256) void k1_match(
    const float* __restrict__ anchors, const float* __restrict__ gt_boxes,
    float* __restrict__ best_iou, int* __restrict__ best_g,
    unsigned long long* __restrict__ gkey_part, float* __restrict__ acc) {
#pragma clang fp contract(off)
    int b = blockIdx.y;
    int a = blockIdx.x * 256 + threadIdx.x;
    int lane = threadIdx.x & 63;
    if (blockIdx.x == 0 && b == 0 && threadIdx.x < 4)
        ((int*)acc)[threadIdx.x] = 0;            // zero [cls, box, mask, npos]
    __shared__ float sg[GG][4];
    __shared__ unsigned long long s_gk[GG];
    for (int t = threadIdx.x; t < GG * 4; t += 256)
        sg[t >> 2][t & 3] = gt_boxes[b * GG * 4 + t] / 550.0f;
    if (threadIdx.x < GG) s_gk[threadIdx.x] = 0ULL;
    __syncthreads();
    bool valid = a < AA;
    int ac = valid ? a : AA - 1;
    float4 an = ((const float4*)anchors)[ac];
    float ax1 = an.x - an.z * 0.5f, ay1 = an.y - an.w * 0.5f;
    float ax2 = an.x + an.z * 0.5f, ay2 = an.y + an.w * 0.5f;
    float areaA = (ax2 - ax1) * (ay2 - ay1);
    unsigned long long bk = 0ULL;   // (vbits<<6)|(31-g): max => first-max argmax
    for (int gg = 0; gg < GG; ++gg) {
        int g = (gg + lane) & (GG - 1);          // stagger: 32 distinct LDS slots
        float v = iou_one(ax1, ay1, ax2, ay2, areaA, sg[g][0], sg[g][1], sg[g][2], sg[g][3]);
        unsigned vb = __float_as_uint(v);        // v >= 0 -> order-preserving
        unsigned long long k2 = ((unsigned long long)vb << 6) | (unsigned)(GG - 1 - g);
        if (k2 > bk) bk = k2;
        if (valid) {
            unsigned long long kg =
                ((unsigned long long)vb << 32) | (unsigned)(AA - 1 - a);
            atomicMax(&s_gk[g], kg);
        }
    }
    if (valid) {
        best_iou[b * AA + a] = __uint_as_float((unsigned)(bk >> 6));
        best_g[b * AA + a] = (GG - 1) - (int)(bk & 63ULL);
    }
    __syncthreads();
    if (threadIdx.x < GG)
        gkey_part[((size_t)b * NB1 + blockIdx.x) * GG + threadIdx.x] = s_gk[threadIdx.x];
}

// ---------------------------------------------------------------------------
// K3: per image — reduce per-block gt keys, scatter overrides via an O(1) LDS
// lookup table (ascending g -> last wins, matching XLA scatter), pos
// compaction + keys, hard-negative cap via ballot-based scan, active-row
// compaction. selmask: 0 = unused, 1 = neg, 2 = pos.
// ---------------------------------------------------------------------------
__global__ __launch_bounds__(1024) void k3_match_scan(
    const float* __restrict__ best_iou, const int* __restrict__ best_g_in,
    const unsigned long long* __restrict__ gkey_part,
    int* __restrict__ gidx_out, int* __restrict__ selmask,
    unsigned long long* __restrict__ pos_key,
    int* __restrict__ pos_cnt, int* __restrict__ g_npos,
    int* __restrict__ act_list, int* __restrict__ act_cnt) {
#pragma clang fp contract(off)
    int b = blockIdx.x;
    int tid = threadIdx.x;
    int lane = tid & 63, wid = tid >> 6;
    __shared__ short s_ov[AA];                  // override g per anchor, -1 none
    __shared__ unsigned long long s_gmax[GG];
    __shared__ int sba[GG];
    __shared__ unsigned long long s_pmask[NWCH];
    __shared__ unsigned long long s_nmask[NWCH];
    __shared__ int s_woff[NWCH];
    __shared__ int s_wred[5];
    __shared__ int s_cnt, s_act;
    for (int i = tid; i < AA; i += 1024) s_ov[i] = -1;
    if (tid < GG) s_gmax[tid] = 0ULL;
    if (tid == 0) { s_cnt = 0; s_act = 0; }
    __syncthreads();
    // reduce 76 per-block partial keys per g (32 g x 32 groups)
    for (int c = tid >> 5; c < NB1; c += 32)
        atomicMax(&s_gmax[tid & 31],
                  gkey_part[((size_t)b * NB1 + c) * GG + (tid & 31)]);
    __syncthreads();
    if (tid < GG) sba[tid] = AA - 1 - (int)(unsigned)(s_gmax[tid] & 0xffffffffULL);
    __syncthreads();
    if (tid == 0) {
        for (int g = 0; g < GG; ++g) s_ov[sba[g]] = (short)g;  // ascending: last wins
    }
    __syncthreads();

    // pass 1: matching decisions + pos keys + per-wave-chunk ballots
    for (int base = 0; base < AA; base += 1024) {
        int a = base + tid;
        bool p = false, npre = false;
        if (a < AA) {
            float biou = best_iou[b * AA + a];
            int ov = s_ov[a];
            int gi = (ov >= 0) ? ov : best_g_in[b * AA + a];
            p = (biou >= 0.5f) || (ov >= 0);
            npre = (biou < 0.4f) && !p;
            gidx_out[b * AA + a] = gi;
            selmask[b * AA + a] = p ? 2 : (npre ? 1 : 0);
            if (p) {
                int slot = atomicAdd(&s_cnt, 1);
                unsigned vb = __float_as_uint(biou + 1.0f);   // >= 0x3F800000
                unsigned long long key =
                    ((unsigned long long)(vb - 0x3F800000u) << 32) |
                    (unsigned)(AA - 1 - a);
                pos_key[(size_t)b * AA + slot] = key;
            }
        }
        unsigned long long pm = __ballot(p);
        unsigned long long nm = __ballot(npre);
        if (lane == 0) {
            int w = (base >> 6) + wid;
            s_pmask[w] = pm;
            s_nmask[w] = nm;
        }
    }
    __syncthreads();
    int npos = s_cnt;
    if (tid == 0) { pos_cnt[b] = npos; atomicAdd(g_npos, npos); }
    int cap = npos * NEGRATIO;

    // scan 304 chunk counts with 5 waves
    int c = (tid < NWCH) ? __popcll(s_nmask[tid]) : 0;
    int inc = c;
    if (wid < 5) {
        #pragma unroll
        for (int d = 1; d < 64; d <<= 1) {
            int t = __shfl_up(inc, d);
            if (lane >= d) inc += t;
        }
        if (lane == 63) s_wred[wid] = inc;
    }
    __syncthreads();
    if (tid == 0) {
        int run = 0;
        #pragma unroll
        for (int i = 0; i < 5; ++i) { int t = s_wred[i]; s_wred[i] = run; run += t; }
    }
    __syncthreads();
    if (tid < NWCH) s_woff[tid] = inc - c + s_wred[wid];   // exclusive prefix
    __syncthreads();

    // pass 2: drop negs beyond cap, compact active rows (order-free)
    for (int base = 0; base < AA; base += 1024) {
        int a = base + tid;
        int w = (base >> 6) + wid;
        unsigned long long nm = s_nmask[w], pm = s_pmask[w];
        bool npre = (nm >> lane) & 1ULL;
        bool pos  = (pm >> lane) & 1ULL;
        int rank = __popcll(nm & ((1ULL << lane) - 1ULL));
        bool kept = npre && (s_woff[w] + rank + 1 <= cap);
        if (a < AA) {
            if (npre && !kept) selmask[b * AA + a] = 0;
            if (pos || kept) {
                int slot = atomicAdd(&s_act, 1);
                act_list[b * AA + slot] = a;
            }
        }
    }
    __syncthreads();
    if (tid == 0) act_cnt[b] = s_act;
}

// ---------------------------------------------------------------------------
// K45: focal classification + box loss fused over the compacted active list.
// One 64-lane group per row; lane 0 adds the box term for positive rows.
// Per-block LDS reduction -> one atomic per block per accumulator.
// ---------------------------------------------------------------------------
#define K45BLK 128
__global__ __launch_bounds__(256) void k45_cls_box(
    const float* __restrict__ cls_p, const int* __restrict__ gtl,
    const int* __restrict__ gidx, const int* __restrict__ selmask,
    const int* __restrict__ act_list, const int* __restrict__ act_cnt,
    const float* __restrict__ box_p, const float* __restrict__ anchors,
    const float* __restrict__ gt_boxes, float* __restrict__ acc) {
    int b = blockIdx.y;
    int n = act_cnt[b];
    int group = blockIdx.x * 4 + (threadIdx.x >> 6);
    int lane = threadIdx.x & 63;
    float fsum = 0.0f, bsum = 0.0f;
    for (int i = group; i < n; i += K45BLK * 4) {
        int a = act_list[b * AA + i];
        int r = b * AA + a;
        const float* x = cls_p + (size_t)r * CC;
        float e0 = x[lane];
        float e1 = (lane < CC - 64) ? x[64 + lane] : -3.0e38f;
        float m = fmaxf(e0, e1);
        for (int off = 32; off; off >>= 1) m = fmaxf(m, __shfl_xor(m, off));
        float s = expf(e0 - m) + ((lane < CC - 64) ? expf(e1 - m) : 0.0f);
        for (int off = 32; off; off >>= 1) s += __shfl_xor(s, off);
        if (lane == 0) {
            int sm = selmask[r];
            int g = gidx[r];
            int lbl = (sm == 2) ? gtl[b * GG + g] : 0;
            float pt = expf(x[lbl] - m) / s;
            pt = fminf(fmaxf(pt, 1e-6f), 1.0f - 1e-6f);
            float at = (lbl > 0) ? 0.25f : 0.75f;
            float om = 1.0f - pt;
            fsum += at * om * om * (-logf(pt));
            if (sm == 2) {
                float m0 = gt_boxes[(b * GG + g) * 4 + 0] / 550.0f;
                float m1 = gt_boxes[(b * GG + g) * 4 + 1] / 550.0f;
                float m2 = gt_boxes[(b * GG + g) * 4 + 2] / 550.0f;
                float m3 = gt_boxes[(b * GG + g) * 4 + 3] / 550.0f;
                float4 an = ((const float4*)anchors)[a];
                float gcx = 0.5f * (m0 + m2), gcy = 0.5f * (m1 + m3);
                float gw = fmaxf(m2 - m0, 1e-6f), gh = fmaxf(m3 - m1, 1e-6f);
                float t0 = (gcx - an.x) / (an.z * 0.1f);
                float t1 = (gcy - an.y) / (an.w * 0.1f);
                float t2 = logf(gw / an.z) / 0.2f;
                float t3 = logf(gh / an.w) / 0.2f;
                const float* bp = box_p + (size_t)r * 4;
                float d;
                d = fabsf(bp[0] - t0); bsum += (d < 1.0f) ? 0.5f * d * d : d - 0.5f;
                d = fabsf(bp[1] - t1); bsum += (d < 1.0f) ? 0.5f * d * d : d - 0.5f;
                d = fabsf(bp[2] - t2); bsum += (d < 1.0f) ? 0.5f * d * d : d - 0.5f;
                d = fabsf(bp[3] - t3); bsum += (d < 1.0f) ? 0.5f * d * d : d - 0.5f;
            }
        }
    }
    __shared__ float s4f[4], s4b[4];
    if (lane == 0) { s4f[threadIdx.x >> 6] = fsum; s4b[threadIdx.x >> 6] = bsum; }
    __syncthreads();
    if (threadIdx.x == 0) {
        atomicAdd(acc + 0, s4f[0] + s4f[1] + s4f[2] + s4f[3]);
        atomicAdd(acc + 1, s4b[0] + s4b[1] + s4b[2] + s4b[3]);
    }
}

// ---------------------------------------------------------------------------
// K6: per-image top-min(npos,128) via MSB-first radix select on unique 56-bit
// keys, then counting-sort selection by matched gt index g (order within the
// selection is free — commutative sum, all weights 1). Gathers coeffs + g.
// ---------------------------------------------------------------------------
__global__ __launch_bounds__(1024) void k6_select(
    const unsigned long long* __restrict__ pos_key, const int* __restrict__ pos_cnt,
    const int* __restrict__ gidx, const float* __restrict__ coeffs,
    int* __restrict__ sel_g, float* __restrict__ sel_coef, int* __restrict__ sel_cnt) {
    int b = blockIdx.x, tid = threadIdx.x;
    __shared__ unsigned long long s_keys[SELCAP];
    __shared__ int s_hist[256];
    __shared__ int s_sfx[256];
    __shared__ int s_wsum[4];
    __shared__ unsigned long long s_prefix;
    __shared__ int s_kk;
    __shared__ int s_nsel;
    __shared__ int s_sel_a[KPOS];
    __shared__ int s_sorted_a[KPOS];
    __shared__ int s_sorted_g[KPOS];
    __shared__ int s_gcnt[GG];

    int n = pos_cnt[b];
    int K = (n < KPOS) ? n : KPOS;
    const unsigned long long* keys;
    if (n <= SELCAP) {
        for (int i = tid; i < n; i += 1024) s_keys[i] = pos_key[(size_t)b * AA + i];
        keys = s_keys;
    } else {
        keys = pos_key + (size_t)b * AA;
    }
    if (tid == 0) { s_prefix = 0ULL; s_kk = KPOS; s_nsel = 0; }
    __syncthreads();

    if (n > KPOS) {
        for (int d = 6; d >= 0; --d) {
            unsigned long long pref = s_prefix;   // snapshot (post-barrier)
            int kk = s_kk;
            if (tid < 256) s_hist[tid] = 0;
            __syncthreads();
            unsigned long long mhi = ~((1ULL << (8 * (d + 1))) - 1ULL);
            for (int i = tid; i < n; i += 1024) {
                unsigned long long k = keys[i];
                if ((k & mhi) == pref)
                    atomicAdd(&s_hist[(int)((k >> (8 * d)) & 255)], 1);
            }
            __syncthreads();
            int x = 0;
            if (tid < 256) {
                x = s_hist[255 - tid];
                #pragma unroll
                for (int o = 1; o < 64; o <<= 1) {
                    int t = __shfl_up(x, o);
                    if ((tid & 63) >= o) x += t;
                }
                if ((tid & 63) == 63) s_wsum[tid >> 6] = x;
            }
            __syncthreads();
            if (tid == 0) {
                int run = 0;
                #pragma unroll
                for (int i = 0; i < 4; ++i) { int t = s_wsum[i]; s_wsum[i] = run; run += t; }
            }
            __syncthreads();
            if (tid < 256) s_sfx[255 - tid] = x + s_wsum[tid >> 6];
            __syncthreads();
            if (tid < 256) {
                int v = tid;
                int ge = s_sfx[v];
                int gt = (v == 255) ? 0 : s_sfx[v + 1];
                if (ge >= kk && gt < kk) {
                    s_prefix = pref | ((unsigned long long)v << (8 * d));
                    s_kk = kk - gt;
                }
            }
            __syncthreads();
        }
    }

    unsigned long long T = (n > KPOS) ? s_prefix : 0ULL;
    for (int i = tid; i < n; i += 1024) {
        unsigned long long k = keys[i];
        if (k >= T) {
            int slot = atomicAdd(&s_nsel, 1);
            if (slot < KPOS)
                s_sel_a[slot] = AA - 1 - (int)(unsigned)(k & 0xffffffffu);
        }
    }
    __syncthreads();

    if (tid < GG) s_gcnt[tid] = 0;
    __syncthreads();
    int mya = -1, myg = -1;
    if (tid < K) {
        mya = s_sel_a[tid];
        myg = gidx[b * AA + mya];
        atomicAdd(&s_gcnt[myg], 1);
    }
    __syncthreads();
    if (tid == 0) {
        int run = 0;
        for (int g = 0; g < GG; ++g) { int c = s_gcnt[g]; s_gcnt[g] = run; run += c; }
    }
    __syncthreads();
    if (tid < K) {
        int pos = atomicAdd(&s_gcnt[myg], 1);
        s_sorted_a[pos] = mya;
        s_sorted_g[pos] = myg;
    }
    __syncthreads();

    if (tid == 0) sel_cnt[b] = K;
    for (int t = tid; t < K * PP; t += 1024) {
        int k = t >> 5, p = t & 31;
        int a = s_sorted_a[k];
        sel_coef[(b * KPOS + k) * PP + p] = coeffs[((size_t)(b * AA + a)) * PP + p];
    }
    for (int t = tid; t < K; t += 1024)
        sel_g[b * KPOS + t] = s_sorted_g[t];
}

// ---------------------------------------------------------------------------
// K7: mask loss. 4 px/thread (float4); KSPLIT=8 K-blocks of 16 k's.
// The 32 proto float4s are PINNED into VGPRs with an opaque inline-asm pass —
// rounds 5-7 showed the register allocator rematerializes const loads inside
// the k-loop (VGPR stuck at 92, ~2.5 GB of L1 traffic, 50 us). An opaque def
// cannot be rematerialized, so protos stay register-resident (~170 VGPR,
// 2 blocks/CU under __launch_bounds__(256,2)).
// ---------------------------------------------------------------------------
__device__ __forceinline__ float4 fma4(float s, float4 p, float4 a) {
    a.x += s * p.x; a.y += s * p.y; a.z += s * p.z; a.w += s * p.w;
    return a;
}
__device__ __forceinline__ float4 add4(float4 a, float4 b) {
    a.x += b.x; a.y += b.y; a.z += b.z; a.w += b.w;
    return a;
}
__device__ __forceinline__ float4 bce4(float4 l, float4 t, float4 a) {
    a.x += fmaxf(l.x, 0.f) - l.x * t.x + __logf(1.f + __expf(-fabsf(l.x)));
    a.y += fmaxf(l.y, 0.f) - l.y * t.y + __logf(1.f + __expf(-fabsf(l.y)));
    a.z += fmaxf(l.z, 0.f) - l.z * t.z + __logf(1.f + __expf(-fabsf(l.z)));
    a.w += fmaxf(l.w, 0.f) - l.w * t.w + __logf(1.f + __expf(-fabsf(l.w)));
    return a;
}

__global__ __launch_bounds__(256, 2) void k7_mask(
    const float* __restrict__ protos, const float* __restrict__ gtm,
    const float* __restrict__ sel_coef, const int* __restrict__ sel_g,
    const int* __restrict__ sel_cnt, float* __restrict__ acc_mask) {
    int b = blockIdx.z;
    int nk = sel_cnt[b];
    int k0 = blockIdx.y * KBLK;
    if (k0 >= nk) return;                       // uniform early-exit, pre-barrier
    int nkb = min(nk, k0 + KBLK) - k0;
    int tid = threadIdx.x;
    int pix0 = (blockIdx.x * 256 + tid) * 4;

    __shared__ float s_c[KBLK * PP];
    __shared__ int s_g[KBLK];
    __shared__ float s_red[4];
    for (int t = tid; t < nkb * PP; t += 256)
        s_c[t] = sel_coef[(b * KPOS + k0) * PP + t];
    for (int t = tid; t < nkb; t += 256)
        s_g[t] = sel_g[b * KPOS + k0 + t];
    __syncthreads();

    bool valid = pix0 < PHW;
    int pc = valid ? pix0 : 0;
    float4 pr[PP];
    #pragma unroll
    for (int p = 0; p < PP; ++p)
        pr[p] = *(const float4*)&protos[((size_t)(b * PP + p)) * PHW + pc];
    // Pin: opaque defs can't be rematerialized -> protos stay in VGPRs.
    #pragma unroll
    for (int p = 0; p < PP; ++p)
        asm volatile("" : "+v"(pr[p].x), "+v"(pr[p].y), "+v"(pr[p].z), "+v"(pr[p].w));
    const float* gtm_b = gtm + (size_t)b * GG * PHW + pc;

    float4 acc4 = make_float4(0.f, 0.f, 0.f, 0.f);
    float4 t4 = make_float4(0.f, 0.f, 0.f, 0.f);
    int gprev = -1;
    for (int k = 0; k < nkb; ++k) {
        const float4* c = (const float4*)&s_c[k * PP];
        float4 a0 = make_float4(0.f, 0.f, 0.f, 0.f), b0 = a0;
        #pragma unroll
        for (int q = 0; q < 8; ++q) {
            float4 u = c[q];
            a0 = fma4(u.x, pr[4 * q + 0], a0); b0 = fma4(u.y, pr[4 * q + 1], b0);
            a0 = fma4(u.z, pr[4 * q + 2], a0); b0 = fma4(u.w, pr[4 * q + 3], b0);
        }
        float4 l = add4(a0, b0);
        int g0 = s_g[k];
        if (g0 != gprev) { t4 = *(const float4*)&gtm_b[(size_t)g0 * PHW]; gprev = g0; }
        acc4 = bce4(l, t4, acc4);
    }

    float acc = valid ? (acc4.x + acc4.y + acc4.z + acc4.w) : 0.0f;
    for (int off = 32; off; off >>= 1) acc += __shfl_xor(acc, off);
    if ((tid & 63) == 0) s_red[tid >> 6] = acc;
    __syncthreads();
    if (tid == 0)
        atomicAdd(acc_mask, s_red[0] + s_red[1] + s_red[2] + s_red[3]);
}

// ---------------------------------------------------------------------------
// K8: finalize.
// ---------------------------------------------------------------------------
__global__ void k8_final(const float* __restrict__ acc, const int* __restrict__ npos,
                         float* __restrict__ out) {
    float denom = fmaxf((float)(*npos), 1.0f);
    out[0] = (1.0f * acc[0] + 1.5f * acc[1] + 6.125f * (acc[2] / (float)PHW)) / denom;
}

// ---------------------------------------------------------------------------
extern "C" void kernel_launch(void* const* d_in, const int* in_sizes, int n_in,
                              void* d_out, int out_size, void* d_ws, size_t ws_size,
                              hipStream_t stream) {
    (void)in_sizes; (void)n_in; (void)out_size; (void)ws_size;
    const float* class_preds = (const float*)d_in[0];
    const float* box_preds   = (const float*)d_in[1];
    const float* mask_coeffs = (const float*)d_in[2];
    const float* prototypes  = (const float*)d_in[3];
    const float* anchors     = (const float*)d_in[4];
    const float* gt_boxes    = (const float*)d_in[5];
    const int*   gt_labels   = (const int*)d_in[6];
    const float* gt_masks    = (const float*)d_in[7];
    float* out = (float*)d_out;

    size_t off = 0;
    char* w = (char*)d_ws;
    auto take = [&](size_t bytes) -> char* {
        char* p = w + off;
        off += (bytes + 255) & ~(size_t)255;
        return p;
    };
    float* acc      = (float*)take(32);                       // [cls, box, mask, npos(int)]
    float* best_iou = (float*)take((size_t)BB * AA * 4);
    int*   best_g   = (int*)  take((size_t)BB * AA * 4);
    int*   gidx     = (int*)  take((size_t)BB * AA * 4);
    int*   selmask  = (int*)  take((size_t)BB * AA * 4);
    unsigned long long* gkey_part =
        (unsigned long long*)take((size_t)BB * NB1 * GG * 8);
    int*   pos_cnt  = (int*)  take((size_t)BB * 4);
    unsigned long long* pos_key = (unsigned long long*)take((size_t)BB * AA * 8);
    int*   sel_g    = (int*)  take((size_t)BB * KPOS * 4);
    int*   sel_cnt  = (int*)  take((size_t)BB * 4);
    float* sel_coef = (float*)take((size_t)BB * KPOS * PP * 4);
    int*   act_list = (int*)  take((size_t)BB * AA * 4);
    int*   act_cnt  = (int*)  take((size_t)BB * 4);

    k1_match<<<dim3(NB1, BB), 256, 0, stream>>>(
        anchors, gt_boxes, best_iou, best_g, gkey_part, acc);
    k3_match_scan<<<BB, 1024, 0, stream>>>(
        best_iou, best_g, gkey_part, gidx, selmask, pos_key, pos_cnt, (int*)(acc + 3),
        act_list, act_cnt);
    k45_cls_box<<<dim3(K45BLK, BB), 256, 0, stream>>>(
        class_preds, gt_labels, gidx, selmask, act_list, act_cnt,
        box_preds, anchors, gt_boxes, acc);
    k6_select<<<BB, 1024, 0, stream>>>(
        pos_key, pos_cnt, gidx, mask_coeffs, sel_g, sel_coef, sel_cnt);
    k7_mask<<<dim3((PHW + 1023) / 1024, KSPLIT, BB), 256, 0, stream>>>(
        prototypes, gt_masks, sel_coef, sel_g, sel_cnt, acc + 2);
    k8_final<<<1, 1, 0, stream>>>(acc, (int*)(acc + 3), out);
}